// Round 16
// baseline (55.692 us; speedup 1.0000x reference)
//
#include <hip/hip_runtime.h>

#define NEG_SLOPE 0.2f

typedef __bf16 bf16x8 __attribute__((ext_vector_type(8)));
typedef float  f32x4  __attribute__((ext_vector_type(4)));
typedef float  f32x2  __attribute__((ext_vector_type(2)));

__device__ __forceinline__ float relu_f(float v) { return v > 0.f ? v : 0.f; }
__device__ __forceinline__ f32x2 pk_fma(f32x2 a, f32x2 b, f32x2 c) { return __builtin_elementwise_fma(a, b, c); }
__device__ __forceinline__ f32x2 pk_max(f32x2 a, f32x2 b) { return __builtin_elementwise_max(a, b); }
__device__ __forceinline__ f32x2 splat2(float s) { f32x2 r = {s, s}; return r; }
__device__ __forceinline__ f32x2 ld2(const float* p) { return *reinterpret_cast<const f32x2*>(p); }

// ---------------- prep: W1/W2 -> bf16 MFMA B-fragment order in d_ws (validated R7-R15) ----
__global__ __launch_bounds__(256)
void prep_weights(const float* __restrict__ W1, const float* __restrict__ W2,
                  __bf16* __restrict__ W1F, __bf16* __restrict__ W2F)
{
    int idx = blockIdx.x * 256 + threadIdx.x;   // 0..8191
    int half = idx >> 12;                        // 0: W1, 1: W2
    int e    = idx & 4095;
    int j   = e & 7;
    int l   = (e >> 3) & 63;
    int t   = e >> 9;                            // 0..7
    int l15 = l & 15;
    int l4  = l >> 4;
    if (half == 0) {
        W1F[e] = (__bf16)W1[(l4 * 8 + j) * 128 + t * 16 + l15];
    } else {
        int ks = t >> 1, nn = t & 1;
        W2F[e] = (__bf16)W2[(j * 16 + ks * 4 + l4) * 32 + nn * 16 + l15];
    }
}

// input-region offsets (floats) inside the overlay buffer; odd strides 7/13/19 are
// coprime with 32 banks -> wave64 scalar reads = 2 lanes/bank = conflict-free.
#define IN_AP 0        // [64][7]
#define IN_AV 448      // [64][7]
#define IN_RL 896      // [64][19]
#define IN_OP 2112     // [64][13]
#define IN_LM 2944     // [64][19]  (end 4160 floats = 16640 B <= 17408)

// ============ Fused kernel: GAT + MLP; coalesced LDS input staging ============
// R16 change vs R15 (validated): phase-1 inputs staged into LDS with ~15 fully
// coalesced dword loads/thread (ONE latency window), replacing ~18-27 narrow
// lane-strided VMEM loads/thread (the ~20 us stall constant across R8-R15).
// z overlays the dead input region after B2 (two barriers in between).
// LDS: wred 2304 + lp 9216 + h 5120 + big 17408 = 34048 B -> 4 blocks/CU.
__global__ __launch_bounds__(256)
void scl_fused_kernel(
    const float* __restrict__ agent_pos, const float* __restrict__ agent_vel,
    const float* __restrict__ rel_lm, const float* __restrict__ other_pos,
    const float* __restrict__ lm_pos,
    const float* __restrict__ Wl, const float* __restrict__ bl,
    const float* __restrict__ Wr, const float* __restrict__ br,
    const float* __restrict__ We, const float* __restrict__ att,
    const float* __restrict__ bias,
    const bf16x8* __restrict__ W1F, const float* __restrict__ b1,
    const bf16x8* __restrict__ W2F, const float* __restrict__ b2,
    float* __restrict__ out, int Btot)
{
    __shared__ alignas(16) float  lds_wred[2][3][6][16];   // [side l/r][node j][pos k][ch]
    __shared__ alignas(16) float  lds_lp[2304];            // lp[2][2][64][9] f32
    __shared__ alignas(16) __bf16 lds_h[64][40];           // pooled GAT out
    __shared__ alignas(16) char   lds_big[17408];          // phase<=1: inputs; phase 2: z[4][16][136]

    const int tid  = threadIdx.x;
    const int lane = tid & 63;
    const int w    = tid >> 6;
    const int g    = __builtin_amdgcn_readfirstlane(w & 1);
    const int ch   = __builtin_amdgcn_readfirstlane((w >> 1) & 1);
    const int wu   = __builtin_amdgcn_readfirstlane(w);
    const int CB   = ch * 8;

    const int blk = blockIdx.x * 64;
    int nS = Btot - blk; if (nS > 64) nS = 64;
    int sl = lane; if (sl >= nS) sl = nS - 1;   // lane-local clamp (in-block data only)

    const int o0[3] = {1, 0, 0};
    const int o1[3] = {2, 2, 1};

    // ---- fragment loads (coalesced 16B/lane; consumed only in phase 2) ----
    bf16x8 w1f[8], w2f[8];
#pragma unroll
    for (int n = 0; n < 8; ++n) w1f[n] = W1F[(n << 6) | lane];
#pragma unroll
    for (int t = 0; t < 8; ++t) w2f[t] = W2F[(t << 6) | lane];

    // ---------- phase 0a: stage block inputs (coalesced) ----------
    {
        float* in = (float*)lds_big;
        for (int i = tid; i < nS * 6; i += 256) {
            int s = i / 6, k = i - s * 6;
            in[IN_AP + s * 7 + k] = agent_pos[(size_t)blk * 6 + i];
        }
        for (int i = tid; i < nS * 6; i += 256) {
            int s = i / 6, k = i - s * 6;
            in[IN_AV + s * 7 + k] = agent_vel[(size_t)blk * 6 + i];
        }
        for (int i = tid; i < nS * 18; i += 256) {
            int s = i / 18, k = i - s * 18;
            in[IN_RL + s * 19 + k] = rel_lm[(size_t)blk * 18 + i];
        }
        for (int i = tid; i < nS * 12; i += 256) {
            int s = i / 12, k = i - s * 12;
            in[IN_OP + s * 13 + k] = other_pos[(size_t)blk * 12 + i];
        }
        for (int i = tid; i < nS * 18; i += 256) {
            int s = i / 18, k = i - s * 18;
            in[IN_LM + s * 19 + k] = lm_pos[(size_t)blk * 18 + i];
        }
    }
    // ---------- phase 0b: reduced g=1 transform matrices (exact algebra) ----
    if (tid < 192) {
#pragma unroll
        for (int q = 0; q < 3; ++q) {
            int e = tid * 3 + q;            // 0..575
            int c = e & 15;
            int r16 = e >> 4;               // (side*3+j)*6+k
            int k = r16 % 6, sj = r16 / 6, j = sj % 3, side = sj / 3;
            const float* Wm = side ? Wr : Wl;
            int m = k >> 1, isY = k & 1;
            float v = Wm[(4 + 2 * m + isY) * 16 + c];
            if (m == o0[j]) v += Wm[(10 + isY) * 16 + c];
            if (m == o1[j]) v += Wm[(12 + isY) * 16 + c];
            if (m == j)
                v += Wm[(0 + isY) * 16 + c] - Wm[(4 + isY) * 16 + c]
                   - Wm[(6 + isY) * 16 + c] - Wm[(8 + isY) * 16 + c]
                   - Wm[(10 + isY) * 16 + c] - Wm[(12 + isY) * 16 + c];
            lds_wred[side][j][k][c] = v;
        }
    }
    __syncthreads();    // B0: inputs + wred ready

    // ---------- phase 1: GAT (reads from LDS only) ----------
    const float* in = (const float*)lds_big;
    float px[3], py[3];
    f32x2 xl[3][4], xr[3][4];

    if (g == 0) {
#pragma unroll
        for (int j = 0; j < 3; ++j) {
            px[j] = in[IN_AP + sl * 7 + 2 * j];
            py[j] = in[IN_AP + sl * 7 + 2 * j + 1];
        }
        float xf[3][14];
#pragma unroll
        for (int j = 0; j < 3; ++j) {
            xf[j][0] = px[j]; xf[j][1] = py[j];
            xf[j][2] = in[IN_AV + sl * 7 + 2 * j];
            xf[j][3] = in[IN_AV + sl * 7 + 2 * j + 1];
#pragma unroll
            for (int k = 0; k < 6; ++k) xf[j][4 + k] = in[IN_RL + sl * 19 + j * 6 + k];
#pragma unroll
            for (int k = 0; k < 4; ++k) xf[j][10 + k] = in[IN_OP + sl * 13 + j * 4 + k];
        }
#pragma unroll
        for (int cc = 0; cc < 4; ++cc) {
            f32x2 vbl = ld2(bl + CB + cc * 2), vbr = ld2(br + CB + cc * 2);
#pragma unroll
            for (int j = 0; j < 3; ++j) { xl[j][cc] = vbl; xr[j][cc] = vbr; }
        }
#pragma unroll
        for (int k = 0; k < 14; ++k) {
            f32x2 wl2[4], wr2[4];
#pragma unroll
            for (int cc = 0; cc < 4; ++cc) {
                wl2[cc] = ld2(Wl + k * 16 + CB + cc * 2);
                wr2[cc] = ld2(Wr + k * 16 + CB + cc * 2);
            }
#pragma unroll
            for (int j = 0; j < 3; ++j) {
                f32x2 xk = splat2(xf[j][k]);
#pragma unroll
                for (int cc = 0; cc < 4; ++cc) {
                    xl[j][cc] = pk_fma(xk, wl2[cc], xl[j][cc]);
                    xr[j][cc] = pk_fma(xk, wr2[cc], xr[j][cc]);
                }
            }
        }
    } else {
#pragma unroll
        for (int m = 0; m < 3; ++m) {
            px[m] = in[IN_LM + sl * 19 + 2 * m];
            py[m] = in[IN_LM + sl * 19 + 2 * m + 1];
        }
        float ps[6] = {px[0], py[0], px[1], py[1], px[2], py[2]};
#pragma unroll
        for (int cc = 0; cc < 4; ++cc) {
            f32x2 vbl = ld2(bl + CB + cc * 2), vbr = ld2(br + CB + cc * 2);
#pragma unroll
            for (int j = 0; j < 3; ++j) { xl[j][cc] = vbl; xr[j][cc] = vbr; }
        }
#pragma unroll
        for (int k = 0; k < 6; ++k) {
            f32x2 pk = splat2(ps[k]);
#pragma unroll
            for (int j = 0; j < 3; ++j) {
#pragma unroll
                for (int cc = 0; cc < 4; ++cc) {
                    xl[j][cc] = pk_fma(pk, ld2(&lds_wred[0][j][k][CB + cc * 2]), xl[j][cc]);
                    xr[j][cc] = pk_fma(pk, ld2(&lds_wred[1][j][k][CB + cc * 2]), xr[j][cc]);
                }
            }
        }
    }

    // ---- pairwise distances + edge geometry (e = j*3+i) ----
    float ax[9], ay[9], ad[9];
    {
        float dx, dy, d01, d02, d12;
        dx = px[0] - px[1]; dy = py[0] - py[1]; d01 = sqrtf(dx * dx + dy * dy);
        dx = px[0] - px[2]; dy = py[0] - py[2]; d02 = sqrtf(dx * dx + dy * dy);
        dx = px[1] - px[2]; dy = py[1] - py[2]; d12 = sqrtf(dx * dx + dy * dy);
#pragma unroll
        for (int i = 0; i < 3; ++i) {
#pragma unroll
            for (int j = 0; j < 3; ++j) {
                int e = j * 3 + i;
                if (i == j) {
                    const int a = o0[i], c2 = o1[i];
                    ax[e] = 0.5f * (px[a] + px[c2]) - px[i];
                    ay[e] = 0.5f * (py[a] + py[c2]) - py[i];
                    const float dA = (i == 0) ? d01 : ((i == 1) ? d01 : d02);
                    const float dB = (i == 0) ? d02 : ((i == 1) ? d12 : d12);
                    ad[e] = 0.5f * (dA + dB);
                } else {
                    ax[e] = px[j] - px[i];
                    ay[e] = py[j] - py[i];
                    ad[e] = ((i == 0 && j == 1) || (i == 1 && j == 0)) ? d01
                          : ((i == 0 && j == 2) || (i == 2 && j == 0)) ? d02 : d12;
                }
            }
        }
    }

    // ---- logit partials: cc-outer (validated R14) ----
    f32x2 lpacc[9];
#pragma unroll
    for (int e = 0; e < 9; ++e) lpacc[e] = splat2(0.f);
#pragma unroll
    for (int cc = 0; cc < 4; ++cc) {
        f32x2 we0 = ld2(We + CB + cc * 2);
        f32x2 we1 = ld2(We + 16 + CB + cc * 2);
        f32x2 we2 = ld2(We + 32 + CB + cc * 2);
        f32x2 vat = ld2(att + CB + cc * 2);
#pragma unroll
        for (int j = 0; j < 3; ++j) {
#pragma unroll
            for (int i = 0; i < 3; ++i) {
                int e = j * 3 + i;
                f32x2 gg = xl[j][cc] + xr[i][cc];
                gg = pk_fma(splat2(ax[e]), we0, gg);
                gg = pk_fma(splat2(ay[e]), we1, gg);
                gg = pk_fma(splat2(ad[e]), we2, gg);
                f32x2 lk = pk_max(gg, gg * splat2(NEG_SLOPE));
                lpacc[e] = pk_fma(lk, vat, lpacc[e]);
            }
        }
    }
    float lp[9];
#pragma unroll
    for (int e = 0; e < 9; ++e) lp[e] = lpacc[e].x + lpacc[e].y;

    // ---- exchange partials with sibling channel-half ----
#define LPX(gg, cc2, ss, ee) lds_lp[(((gg) * 2 + (cc2)) * 64 + (ss)) * 9 + (ee)]
#pragma unroll
    for (int e = 0; e < 9; ++e) LPX(g, ch, lane, e) = lp[e];
    __syncthreads();    // B1

    float lg[9];
#pragma unroll
    for (int e = 0; e < 9; ++e) lg[e] = lp[e] + LPX(g, 1 - ch, lane, e);

    // ---- softmax per target (logits O(10), no max-sub) + pooled relu-sum ----
    f32x2 vb[4];
#pragma unroll
    for (int cc = 0; cc < 4; ++cc) vb[cc] = ld2(bias + CB + cc * 2);
    f32x2 hs[4] = {{0,0},{0,0},{0,0},{0,0}};
    const f32x2 zero2 = {0.f, 0.f};
#pragma unroll
    for (int i = 0; i < 3; ++i) {
        float e0 = __expf(lg[i]);
        float e1 = __expf(lg[3 + i]);
        float e2 = __expf(lg[6 + i]);
        float inv = __builtin_amdgcn_rcpf(e0 + e1 + e2);
        f32x2 a0 = splat2(e0 * inv), a1 = splat2(e1 * inv), a2 = splat2(e2 * inv);
#pragma unroll
        for (int cc = 0; cc < 4; ++cc) {
            f32x2 v = pk_fma(a0, xl[0][cc],
                      pk_fma(a1, xl[1][cc],
                      pk_fma(a2, xl[2][cc], vb[cc])));
            hs[cc] += pk_max(v, zero2);
        }
    }

    // ---- publish pooled h as bf16 into LDS ----
    {
        bf16x8 hv;
#pragma unroll
        for (int cc = 0; cc < 4; ++cc) {
            hv[cc * 2 + 0] = (__bf16)hs[cc].x;
            hv[cc * 2 + 1] = (__bf16)hs[cc].y;
        }
        *reinterpret_cast<bf16x8*>(&lds_h[lane][g * 16 + CB]) = hv;
    }
    __syncthreads();    // B2: h ready; inputs dead -> z overlays lds_big

    // ---------- phase 2: MLP via MFMA 16x16x32 bf16 (R8 layout, frags in VGPRs) ----------
    const int l15 = lane & 15;
    const int l4  = lane >> 4;
    const f32x4 zero4 = {0.f, 0.f, 0.f, 0.f};
    __bf16* zb = (__bf16*)lds_big;               // z[4][16][136]

    float b1v[8], b2v[2];
#pragma unroll
    for (int n = 0; n < 8; ++n) b1v[n] = b1[n * 16 + l15];
#pragma unroll
    for (int nn = 0; nn < 2; ++nn) b2v[nn] = b2[nn * 16 + l15];

    // layer 1: z[16x128] = h[16x32] @ W1 + b1, relu
    bf16x8 a1 = *reinterpret_cast<const bf16x8*>(&lds_h[wu * 16 + l15][l4 * 8]);
    f32x4 acc[8];
#pragma unroll
    for (int n = 0; n < 8; ++n)
        acc[n] = __builtin_amdgcn_mfma_f32_16x16x32_bf16(a1, w1f[n], zero4, 0, 0, 0);
#pragma unroll
    for (int r = 0; r < 4; ++r) {
        bf16x8 zv;
#pragma unroll
        for (int n = 0; n < 8; ++n) zv[n] = (__bf16)relu_f(acc[n][r] + b1v[n]);
        *reinterpret_cast<bf16x8*>(&zb[(wu * 16 + l4 * 4 + r) * 136 + l15 * 8]) = zv;
    }

    // layer 2: o[16x32] = z @ W2 + b2 (same-wave z reuse, compiler waits lgkmcnt)
    f32x4 o2[2] = {zero4, zero4};
#pragma unroll
    for (int ks = 0; ks < 4; ++ks) {
        bf16x8 a2 = *reinterpret_cast<const bf16x8*>(&zb[(wu * 16 + l15) * 136 + ks * 32 + l4 * 8]);
#pragma unroll
        for (int nn = 0; nn < 2; ++nn)
            o2[nn] = __builtin_amdgcn_mfma_f32_16x16x32_bf16(a2, w2f[ks * 2 + nn], o2[nn], 0, 0, 0);
    }

    // store: lane holds o[l4*4+r][nn*16+l15]
#pragma unroll
    for (int nn = 0; nn < 2; ++nn) {
#pragma unroll
        for (int r = 0; r < 4; ++r) {
            int row = blk + wu * 16 + l4 * 4 + r;
            if (row < Btot)
                out[(size_t)row * 32 + nn * 16 + l15] = o2[nn][r] + b2v[nn];
        }
    }
}

extern "C" void kernel_launch(void* const* d_in, const int* in_sizes, int n_in,
                              void* d_out, int out_size, void* d_ws, size_t ws_size,
                              hipStream_t stream) {
    const float* agent_pos = (const float*)d_in[0];
    const float* agent_vel = (const float*)d_in[1];
    const float* rel_lm    = (const float*)d_in[2];
    const float* other_pos = (const float*)d_in[3];
    const float* lm_pos    = (const float*)d_in[4];
    const float* Wl   = (const float*)d_in[5];
    const float* bl   = (const float*)d_in[6];
    const float* Wr   = (const float*)d_in[7];
    const float* br   = (const float*)d_in[8];
    const float* We   = (const float*)d_in[9];
    const float* att  = (const float*)d_in[10];
    const float* bias = (const float*)d_in[11];
    const float* W1   = (const float*)d_in[12];
    const float* b1   = (const float*)d_in[13];
    const float* W2   = (const float*)d_in[14];
    const float* b2   = (const float*)d_in[15];
    float* out = (float*)d_out;

    __bf16* W1F = (__bf16*)d_ws;                   // 8 KB
    __bf16* W2F = (__bf16*)((char*)d_ws + 8192);   // 8 KB

    prep_weights<<<32, 256, 0, stream>>>(W1, W2, W1F, W2F);

    int B = in_sizes[0] / 6;                  // agent_pos is [B,3,2]
    int grid = (B + 63) / 64;
    scl_fused_kernel<<<grid, 256, 0, stream>>>(
        agent_pos, agent_vel, rel_lm, other_pos, lm_pos,
        Wl, bl, Wr, br, We, att, bias,
        (const bf16x8*)W1F, b1, (const bf16x8*)W2F, b2, out, B);
}

// Round 17
// 45.666 us; speedup vs baseline: 1.2195x; 1.2195x over previous
//
#include <hip/hip_runtime.h>

#define NEG_SLOPE 0.2f

typedef __bf16 bf16x8 __attribute__((ext_vector_type(8)));
typedef __bf16 bf16x4 __attribute__((ext_vector_type(4)));
typedef __bf16 bf16x2 __attribute__((ext_vector_type(2)));
typedef float  f32x4  __attribute__((ext_vector_type(4)));
typedef float  f32x2  __attribute__((ext_vector_type(2)));

__device__ __forceinline__ float relu_f(float v) { return v > 0.f ? v : 0.f; }
__device__ __forceinline__ f32x2 pk_fma(f32x2 a, f32x2 b, f32x2 c) { return __builtin_elementwise_fma(a, b, c); }
__device__ __forceinline__ f32x2 pk_max(f32x2 a, f32x2 b) { return __builtin_elementwise_max(a, b); }
__device__ __forceinline__ f32x2 splat2(float s) { f32x2 r = {s, s}; return r; }
__device__ __forceinline__ f32x2 ld2(const float* p) { return *reinterpret_cast<const f32x2*>(p); }

// ---------------- prep: weight fragments into d_ws ----------------
// W1F/W2F: validated R7-R15 MLP fragments.
// WTF (new): transform B-frags for x[.,32pad] @ [Wl|Wr]: B[k][nt*16+n]:
//   k<14 -> Wl/Wr[k][n]; k==14 -> bl/br[n] (bias folded via constant-1 feature);
//   k>14 -> 0.  WTF[(nt*64+l)*8+j] = B[l4*8+j][nt*16+l15].
__global__ __launch_bounds__(256)
void prep_weights(const float* __restrict__ Wl, const float* __restrict__ bl,
                  const float* __restrict__ Wr, const float* __restrict__ br,
                  const float* __restrict__ W1, const float* __restrict__ W2,
                  __bf16* __restrict__ W1F, __bf16* __restrict__ W2F,
                  __bf16* __restrict__ WTF)
{
    int idx = blockIdx.x * 256 + threadIdx.x;   // 0..9215
    if (idx < 4096) {
        int e = idx; int j = e & 7, l = (e >> 3) & 63, t = e >> 9;
        int l15 = l & 15, l4 = l >> 4;
        W1F[e] = (__bf16)W1[(l4 * 8 + j) * 128 + t * 16 + l15];
    } else if (idx < 8192) {
        int e = idx - 4096; int j = e & 7, l = (e >> 3) & 63, t = e >> 9;
        int l15 = l & 15, l4 = l >> 4;
        int ks = t >> 1, nn = t & 1;
        W2F[e] = (__bf16)W2[(j * 16 + ks * 4 + l4) * 32 + nn * 16 + l15];
    } else {
        int e = idx - 8192; int j = e & 7, l = (e >> 3) & 63, nt = e >> 9;  // 0..1
        int l15 = l & 15, l4 = l >> 4;
        int k = l4 * 8 + j;
        float v = 0.f;
        if (k < 14)      v = (nt == 0) ? Wl[k * 16 + l15] : Wr[k * 16 + l15];
        else if (k == 14) v = (nt == 0) ? bl[l15] : br[l15];
        WTF[e] = (__bf16)v;
    }
}

// ============ Fused kernel ============
// Block = 256 threads = 4 waves, 64 samples. wave w -> g=w&1, ch=(w>>1)&1.
// Phase 0a: g0 waves build x-features (incl. constant-1 bias feature) directly
//           into MFMA A-fragment layout xAF[12 mtiles][64 lanes][8] bf16;
//           WRED computed for the g1 path (validated R13-R15).
// Phase 0b: 24 MFMA (6/wave) compute [xl|xr] for all 192 g0 rows -> xlr LDS.
// Phase 1 : g0 reads xl/xr from xlr (+cvt); g1 transforms via WRED (validated).
//           Then edge geometry + cc-outer logits + exchange + softmax (validated).
// Phase 2 : MLP via MFMA (validated R8/R15), z overlays dead xAF region.
// LDS: wred 2304 + lp 9216 + h 5120 + big 26112 = 42752 B -> 3 blocks/CU.
__global__ __launch_bounds__(256)
void scl_fused_kernel(
    const float* __restrict__ agent_pos, const float* __restrict__ agent_vel,
    const float* __restrict__ rel_lm, const float* __restrict__ other_pos,
    const float* __restrict__ lm_pos,
    const float* __restrict__ Wl, const float* __restrict__ bl,
    const float* __restrict__ Wr, const float* __restrict__ br,
    const float* __restrict__ We, const float* __restrict__ att,
    const float* __restrict__ bias,
    const bf16x8* __restrict__ W1F, const float* __restrict__ b1,
    const bf16x8* __restrict__ W2F, const float* __restrict__ b2,
    const bf16x8* __restrict__ WTF,
    float* __restrict__ out, int Btot)
{
    __shared__ alignas(16) float  lds_wred[2][3][6][16];   // [side][node][posk][ch]
    __shared__ alignas(16) float  lds_lp[2304];            // lp[2][2][64][9]
    __shared__ alignas(16) __bf16 lds_h[64][40];           // pooled GAT out
    __shared__ alignas(16) char   lds_big[26112];          // xAF[0,12288)|xlr[12288,26112); z overlays [0,17408)

    const int tid  = threadIdx.x;
    const int lane = tid & 63;
    const int w    = tid >> 6;
    const int g    = __builtin_amdgcn_readfirstlane(w & 1);
    const int ch   = __builtin_amdgcn_readfirstlane((w >> 1) & 1);
    const int wu   = __builtin_amdgcn_readfirstlane(w);
    const int CB   = ch * 8;
    const int l15  = lane & 15;
    const int l4   = lane >> 4;
    const int s    = lane;                     // sample-in-block

    const int blk = blockIdx.x * 64;
    int b = blk + lane;
    if (b >= Btot) b = Btot - 1;               // clamp reads; barriers stay uniform

    const int o0[3] = {1, 0, 0};
    const int o1[3] = {2, 2, 1};
    const f32x4 zero4 = {0.f, 0.f, 0.f, 0.f};

    // ---- fragment loads (coalesced; consumed later) ----
    bf16x8 w1f[8], w2f[8];
#pragma unroll
    for (int n = 0; n < 8; ++n) w1f[n] = W1F[(n << 6) | lane];
#pragma unroll
    for (int t = 0; t < 8; ++t) w2f[t] = W2F[(t << 6) | lane];
    bf16x8 wtf0 = WTF[lane], wtf1 = WTF[64 + lane];

    // ---- positions (early; g-uniform) ----
    float px[3], py[3];
    if (g == 0) {
        const float2* ap = reinterpret_cast<const float2*>(agent_pos + b * 6);
#pragma unroll
        for (int j = 0; j < 3; ++j) { px[j] = ap[j].x; py[j] = ap[j].y; }
    } else {
        const float2* lp2 = reinterpret_cast<const float2*>(lm_pos + b * 18);
#pragma unroll
        for (int m = 0; m < 3; ++m) { px[m] = lp2[m].x; py[m] = lp2[m].y; }
    }

    // ---------- phase 0a: g0 feature build into A-fragment layout ----------
    if (g == 0) {
        bf16x2* xa2 = reinterpret_cast<bf16x2*>(lds_big);
        const int jlo = (ch == 0) ? 0 : 2;
        const int jhi = (ch == 0) ? 2 : 3;
        for (int j = jlo; j < jhi; ++j) {
            float f[14];
            const float2 vel = reinterpret_cast<const float2*>(agent_vel + b * 6)[j];
            const float2* rl = reinterpret_cast<const float2*>(rel_lm + b * 18 + j * 6);
            const float4 op  = reinterpret_cast<const float4*>(other_pos + b * 12)[j];
            f[0] = px[j]; f[1] = py[j];
            f[2] = vel.x; f[3] = vel.y;
            f[4] = rl[0].x; f[5] = rl[0].y;
            f[6] = rl[1].x; f[7] = rl[1].y;
            f[8] = rl[2].x; f[9] = rl[2].y;
            f[10] = op.x; f[11] = op.y; f[12] = op.z; f[13] = op.w;
            const int row = s * 3 + j, mt = row >> 4, r15 = row & 15;
#pragma unroll
            for (int o = 0; o < 4; ++o) {
#pragma unroll
                for (int p = 0; p < 4; ++p) {
                    const int k0 = 8 * o + 2 * p;
                    bf16x2 pr;
                    pr[0] = (k0 < 14) ? (__bf16)f[k0] : ((k0 == 14) ? (__bf16)1.0f : (__bf16)0.f);
                    pr[1] = (k0 + 1 < 14) ? (__bf16)f[k0 + 1] : (__bf16)0.f;
                    xa2[mt * 256 + (o * 16 + r15) * 4 + p] = pr;
                }
            }
        }
    }
    // ---------- phase 0a': WRED for g1 path (validated) ----------
    if (tid < 192) {
#pragma unroll
        for (int q = 0; q < 3; ++q) {
            int e = tid * 3 + q;            // 0..575
            int c = e & 15;
            int r16 = e >> 4;               // (side*3+j)*6+k
            int k = r16 % 6, sj = r16 / 6, j = sj % 3, side = sj / 3;
            const float* Wm = side ? Wr : Wl;
            int m = k >> 1, isY = k & 1;
            float v = Wm[(4 + 2 * m + isY) * 16 + c];
            if (m == o0[j]) v += Wm[(10 + isY) * 16 + c];
            if (m == o1[j]) v += Wm[(12 + isY) * 16 + c];
            if (m == j)
                v += Wm[(0 + isY) * 16 + c] - Wm[(4 + isY) * 16 + c]
                   - Wm[(6 + isY) * 16 + c] - Wm[(8 + isY) * 16 + c]
                   - Wm[(10 + isY) * 16 + c] - Wm[(12 + isY) * 16 + c];
            lds_wred[side][j][k][c] = v;
        }
    }
    __syncthreads();    // B0: xAF + wred ready

    // ---------- phase 0b: transform MFMAs (all 4 waves, 3 mtiles each) ----------
    {
        const __bf16* xa = reinterpret_cast<const __bf16*>(lds_big);
        __bf16* xlr = reinterpret_cast<__bf16*>(lds_big + 12288);
#pragma unroll
        for (int i = 0; i < 3; ++i) {
            const int mt = wu * 3 + i;
            bf16x8 a = *reinterpret_cast<const bf16x8*>(xa + mt * 512 + lane * 8);
            f32x4 d0 = __builtin_amdgcn_mfma_f32_16x16x32_bf16(a, wtf0, zero4, 0, 0, 0);
            f32x4 d1 = __builtin_amdgcn_mfma_f32_16x16x32_bf16(a, wtf1, zero4, 0, 0, 0);
#pragma unroll
            for (int r = 0; r < 4; ++r) {
                const int row = mt * 16 + l4 * 4 + r;
                xlr[row * 36 + l15]      = (__bf16)d0[r];   // xl cols 0-15
                xlr[row * 36 + 16 + l15] = (__bf16)d1[r];   // xr cols 16-31
            }
        }
    }
    __syncthreads();    // B0b: xlr ready

    // ---------- phase 1: per-thread xl/xr ----------
    f32x2 xl[3][4], xr[3][4];
    if (g == 0) {
        const __bf16* xlr = reinterpret_cast<const __bf16*>(lds_big + 12288);
#pragma unroll
        for (int j = 0; j < 3; ++j) {
            const int base = (s * 3 + j) * 36;
            bf16x4 a0 = *reinterpret_cast<const bf16x4*>(xlr + base + CB);
            bf16x4 a1 = *reinterpret_cast<const bf16x4*>(xlr + base + CB + 4);
            bf16x4 r0 = *reinterpret_cast<const bf16x4*>(xlr + base + 16 + CB);
            bf16x4 r1 = *reinterpret_cast<const bf16x4*>(xlr + base + 16 + CB + 4);
            xl[j][0] = (f32x2){(float)a0[0], (float)a0[1]};
            xl[j][1] = (f32x2){(float)a0[2], (float)a0[3]};
            xl[j][2] = (f32x2){(float)a1[0], (float)a1[1]};
            xl[j][3] = (f32x2){(float)a1[2], (float)a1[3]};
            xr[j][0] = (f32x2){(float)r0[0], (float)r0[1]};
            xr[j][1] = (f32x2){(float)r0[2], (float)r0[3]};
            xr[j][2] = (f32x2){(float)r1[0], (float)r1[1]};
            xr[j][3] = (f32x2){(float)r1[2], (float)r1[3]};
        }
    } else {
        float ps[6] = {px[0], py[0], px[1], py[1], px[2], py[2]};
#pragma unroll
        for (int cc = 0; cc < 4; ++cc) {
            f32x2 vbl = ld2(bl + CB + cc * 2), vbr = ld2(br + CB + cc * 2);
#pragma unroll
            for (int j = 0; j < 3; ++j) { xl[j][cc] = vbl; xr[j][cc] = vbr; }
        }
#pragma unroll
        for (int k = 0; k < 6; ++k) {
            f32x2 pk = splat2(ps[k]);
#pragma unroll
            for (int j = 0; j < 3; ++j) {
#pragma unroll
                for (int cc = 0; cc < 4; ++cc) {
                    xl[j][cc] = pk_fma(pk, ld2(&lds_wred[0][j][k][CB + cc * 2]), xl[j][cc]);
                    xr[j][cc] = pk_fma(pk, ld2(&lds_wred[1][j][k][CB + cc * 2]), xr[j][cc]);
                }
            }
        }
    }

    // ---- pairwise distances + edge geometry (e = j*3+i) ----
    float ax[9], ay[9], ad[9];
    {
        float dx, dy, d01, d02, d12;
        dx = px[0] - px[1]; dy = py[0] - py[1]; d01 = sqrtf(dx * dx + dy * dy);
        dx = px[0] - px[2]; dy = py[0] - py[2]; d02 = sqrtf(dx * dx + dy * dy);
        dx = px[1] - px[2]; dy = py[1] - py[2]; d12 = sqrtf(dx * dx + dy * dy);
#pragma unroll
        for (int i = 0; i < 3; ++i) {
#pragma unroll
            for (int j = 0; j < 3; ++j) {
                int e = j * 3 + i;
                if (i == j) {
                    const int a = o0[i], c2 = o1[i];
                    ax[e] = 0.5f * (px[a] + px[c2]) - px[i];
                    ay[e] = 0.5f * (py[a] + py[c2]) - py[i];
                    const float dA = (i == 0) ? d01 : ((i == 1) ? d01 : d02);
                    const float dB = (i == 0) ? d02 : ((i == 1) ? d12 : d12);
                    ad[e] = 0.5f * (dA + dB);
                } else {
                    ax[e] = px[j] - px[i];
                    ay[e] = py[j] - py[i];
                    ad[e] = ((i == 0 && j == 1) || (i == 1 && j == 0)) ? d01
                          : ((i == 0 && j == 2) || (i == 2 && j == 0)) ? d02 : d12;
                }
            }
        }
    }

    // ---- logit partials: cc-outer (validated R14) ----
    f32x2 lpacc[9];
#pragma unroll
    for (int e = 0; e < 9; ++e) lpacc[e] = splat2(0.f);
#pragma unroll
    for (int cc = 0; cc < 4; ++cc) {
        f32x2 we0 = ld2(We + CB + cc * 2);
        f32x2 we1 = ld2(We + 16 + CB + cc * 2);
        f32x2 we2 = ld2(We + 32 + CB + cc * 2);
        f32x2 vat = ld2(att + CB + cc * 2);
#pragma unroll
        for (int j = 0; j < 3; ++j) {
#pragma unroll
            for (int i = 0; i < 3; ++i) {
                int e = j * 3 + i;
                f32x2 gg = xl[j][cc] + xr[i][cc];
                gg = pk_fma(splat2(ax[e]), we0, gg);
                gg = pk_fma(splat2(ay[e]), we1, gg);
                gg = pk_fma(splat2(ad[e]), we2, gg);
                f32x2 lk = pk_max(gg, gg * splat2(NEG_SLOPE));
                lpacc[e] = pk_fma(lk, vat, lpacc[e]);
            }
        }
    }
    float lp[9];
#pragma unroll
    for (int e = 0; e < 9; ++e) lp[e] = lpacc[e].x + lpacc[e].y;

    // ---- exchange partials with sibling channel-half ----
#define LPX(gg, cc2, ss, ee) lds_lp[(((gg) * 2 + (cc2)) * 64 + (ss)) * 9 + (ee)]
#pragma unroll
    for (int e = 0; e < 9; ++e) LPX(g, ch, lane, e) = lp[e];
    __syncthreads();    // B1

    float lg[9];
#pragma unroll
    for (int e = 0; e < 9; ++e) lg[e] = lp[e] + LPX(g, 1 - ch, lane, e);

    // ---- softmax per target (logits O(10), no max-sub) + pooled relu-sum ----
    f32x2 vb[4];
#pragma unroll
    for (int cc = 0; cc < 4; ++cc) vb[cc] = ld2(bias + CB + cc * 2);
    f32x2 hs[4] = {{0,0},{0,0},{0,0},{0,0}};
    const f32x2 zero2 = {0.f, 0.f};
#pragma unroll
    for (int i = 0; i < 3; ++i) {
        float e0 = __expf(lg[i]);
        float e1 = __expf(lg[3 + i]);
        float e2 = __expf(lg[6 + i]);
        float inv = __builtin_amdgcn_rcpf(e0 + e1 + e2);
        f32x2 a0 = splat2(e0 * inv), a1 = splat2(e1 * inv), a2 = splat2(e2 * inv);
#pragma unroll
        for (int cc = 0; cc < 4; ++cc) {
            f32x2 v = pk_fma(a0, xl[0][cc],
                      pk_fma(a1, xl[1][cc],
                      pk_fma(a2, xl[2][cc], vb[cc])));
            hs[cc] += pk_max(v, zero2);
        }
    }

    // ---- publish pooled h as bf16 into LDS ----
    {
        bf16x8 hv;
#pragma unroll
        for (int cc = 0; cc < 4; ++cc) {
            hv[cc * 2 + 0] = (__bf16)hs[cc].x;
            hv[cc * 2 + 1] = (__bf16)hs[cc].y;
        }
        *reinterpret_cast<bf16x8*>(&lds_h[lane][g * 16 + CB]) = hv;
    }
    __syncthreads();    // B2: h ready; xAF/xlr dead -> z overlays lds_big

    // ---------- phase 2: MLP via MFMA 16x16x32 bf16 (validated R8/R15) ----------
    __bf16* zb = reinterpret_cast<__bf16*>(lds_big);   // z[4][16][136]

    float b1v[8], b2v[2];
#pragma unroll
    for (int n = 0; n < 8; ++n) b1v[n] = b1[n * 16 + l15];
#pragma unroll
    for (int nn = 0; nn < 2; ++nn) b2v[nn] = b2[nn * 16 + l15];

    bf16x8 a1 = *reinterpret_cast<const bf16x8*>(&lds_h[wu * 16 + l15][l4 * 8]);
    f32x4 acc[8];
#pragma unroll
    for (int n = 0; n < 8; ++n)
        acc[n] = __builtin_amdgcn_mfma_f32_16x16x32_bf16(a1, w1f[n], zero4, 0, 0, 0);
#pragma unroll
    for (int r = 0; r < 4; ++r) {
        bf16x8 zv;
#pragma unroll
        for (int n = 0; n < 8; ++n) zv[n] = (__bf16)relu_f(acc[n][r] + b1v[n]);
        *reinterpret_cast<bf16x8*>(&zb[((wu * 16 + l4 * 4 + r) * 136) + l15 * 8]) = zv;
    }

    f32x4 o2[2] = {zero4, zero4};
#pragma unroll
    for (int ks = 0; ks < 4; ++ks) {
        bf16x8 a2 = *reinterpret_cast<const bf16x8*>(&zb[((wu * 16 + l15) * 136) + ks * 32 + l4 * 8]);
#pragma unroll
        for (int nn = 0; nn < 2; ++nn)
            o2[nn] = __builtin_amdgcn_mfma_f32_16x16x32_bf16(a2, w2f[ks * 2 + nn], o2[nn], 0, 0, 0);
    }

#pragma unroll
    for (int nn = 0; nn < 2; ++nn) {
#pragma unroll
        for (int r = 0; r < 4; ++r) {
            int row = blk + wu * 16 + l4 * 4 + r;
            if (row < Btot)
                out[(size_t)row * 32 + nn * 16 + l15] = o2[nn][r] + b2v[nn];
        }
    }
}

extern "C" void kernel_launch(void* const* d_in, const int* in_sizes, int n_in,
                              void* d_out, int out_size, void* d_ws, size_t ws_size,
                              hipStream_t stream) {
    const float* agent_pos = (const float*)d_in[0];
    const float* agent_vel = (const float*)d_in[1];
    const float* rel_lm    = (const float*)d_in[2];
    const float* other_pos = (const float*)d_in[3];
    const float* lm_pos    = (const float*)d_in[4];
    const float* Wl   = (const float*)d_in[5];
    const float* bl   = (const float*)d_in[6];
    const float* Wr   = (const float*)d_in[7];
    const float* br   = (const float*)d_in[8];
    const float* We   = (const float*)d_in[9];
    const float* att  = (const float*)d_in[10];
    const float* bias = (const float*)d_in[11];
    const float* W1   = (const float*)d_in[12];
    const float* b1   = (const float*)d_in[13];
    const float* W2   = (const float*)d_in[14];
    const float* b2   = (const float*)d_in[15];
    float* out = (float*)d_out;

    __bf16* W1F = (__bf16*)d_ws;                     // 8 KB
    __bf16* W2F = (__bf16*)((char*)d_ws + 8192);     // 8 KB
    __bf16* WTF = (__bf16*)((char*)d_ws + 16384);    // 2 KB

    prep_weights<<<36, 256, 0, stream>>>(Wl, bl, Wr, br, W1, W2, W1F, W2F, WTF);

    int B = in_sizes[0] / 6;                  // agent_pos is [B,3,2]
    int grid = (B + 63) / 64;
    scl_fused_kernel<<<grid, 256, 0, stream>>>(
        agent_pos, agent_vel, rel_lm, other_pos, lm_pos,
        Wl, bl, Wr, br, We, att, bias,
        (const bf16x8*)W1F, b1, (const bf16x8*)W2F, b2, (const bf16x8*)WTF,
        out, B);
}

// Round 18
// 34.423 us; speedup vs baseline: 1.6179x; 1.3266x over previous
//
#include <hip/hip_runtime.h>

#define NEG_SLOPE 0.2f

typedef __bf16 bf16x8 __attribute__((ext_vector_type(8)));
typedef float  f32x4  __attribute__((ext_vector_type(4)));
typedef float  f32x2  __attribute__((ext_vector_type(2)));

__device__ __forceinline__ float relu_f(float v) { return v > 0.f ? v : 0.f; }
__device__ __forceinline__ f32x2 pk_fma(f32x2 a, f32x2 b, f32x2 c) { return __builtin_elementwise_fma(a, b, c); }
__device__ __forceinline__ f32x2 pk_max(f32x2 a, f32x2 b) { return __builtin_elementwise_max(a, b); }
__device__ __forceinline__ f32x2 splat2(float s) { f32x2 r = {s, s}; return r; }
__device__ __forceinline__ f32x2 ld2(const float* p) { return *reinterpret_cast<const f32x2*>(p); }

// ---------------- prep: W1/W2 -> bf16 MFMA B-fragment order in d_ws (validated R7-R15) ----
__global__ __launch_bounds__(256)
void prep_weights(const float* __restrict__ W1, const float* __restrict__ W2,
                  __bf16* __restrict__ W1F, __bf16* __restrict__ W2F)
{
    int idx = blockIdx.x * 256 + threadIdx.x;   // 0..8191
    int half = idx >> 12;                        // 0: W1, 1: W2
    int e    = idx & 4095;
    int j   = e & 7;
    int l   = (e >> 3) & 63;
    int t   = e >> 9;                            // 0..7
    int l15 = l & 15;
    int l4  = l >> 4;
    if (half == 0) {
        W1F[e] = (__bf16)W1[(l4 * 8 + j) * 128 + t * 16 + l15];
    } else {
        int ks = t >> 1, nn = t & 1;
        W2F[e] = (__bf16)W2[(j * 16 + ks * 4 + l4) * 32 + nn * 16 + l15];
    }
}

// ============ Fused kernel: 16-channel waves (no ch-split, no exchange) ============
// Block = 256 threads = 4 waves, 128 samples. wave w -> g = w&1 (graph),
// sg = w>>1 (sample group). Each thread: one (sample, graph), ALL 16 channels
// as 8x f32x2. vs R13-R15: lp exchange + barrier B1 deleted; geometry/softmax
// computed ONCE per sample-graph (was duplicated per ch-half); lds_lp freed.
// Barriers: B0 (wred), B2 (h). Fragments load after GAT phase (pressure).
// LDS: wred 2304 + h[128][40] 10240 + z[4][16][136] 17408 = 29952 B.
__global__ __launch_bounds__(256)
void scl_fused_kernel(
    const float* __restrict__ agent_pos, const float* __restrict__ agent_vel,
    const float* __restrict__ rel_lm, const float* __restrict__ other_pos,
    const float* __restrict__ lm_pos,
    const float* __restrict__ Wl, const float* __restrict__ bl,
    const float* __restrict__ Wr, const float* __restrict__ br,
    const float* __restrict__ We, const float* __restrict__ att,
    const float* __restrict__ bias,
    const bf16x8* __restrict__ W1F, const float* __restrict__ b1,
    const bf16x8* __restrict__ W2F, const float* __restrict__ b2,
    float* __restrict__ out, int Btot)
{
    __shared__ alignas(16) float  lds_wred[2][3][6][16];   // [side][node][posk][ch]
    __shared__ alignas(16) __bf16 lds_h[128][40];          // pooled GAT out (128 samples)
    __shared__ alignas(16) __bf16 lds_z[4][16][136];       // per-wave z (R8 layout)

    const int tid  = threadIdx.x;
    const int lane = tid & 63;
    const int w    = tid >> 6;
    const int g    = __builtin_amdgcn_readfirstlane(w & 1);
    const int sg   = __builtin_amdgcn_readfirstlane(w >> 1);
    const int wu   = __builtin_amdgcn_readfirstlane(w);
    const int l15  = lane & 15;
    const int l4   = lane >> 4;

    const int blk  = blockIdx.x * 128;
    const int sRow = sg * 64 + lane;            // row in lds_h
    int b = blk + sRow;
    if (b >= Btot) b = Btot - 1;                // clamp reads; barriers stay uniform

    const int o0[3] = {1, 0, 0};
    const int o1[3] = {2, 2, 1};
    const f32x4 zero4 = {0.f, 0.f, 0.f, 0.f};

    // ---------- phase 0: reduced g=1 transform matrices (validated algebra) ----
    if (tid < 192) {
#pragma unroll
        for (int q = 0; q < 3; ++q) {
            int e = tid * 3 + q;            // 0..575
            int c = e & 15;
            int r16 = e >> 4;               // (side*3+j)*6+k
            int k = r16 % 6, sj = r16 / 6, j = sj % 3, side = sj / 3;
            const float* Wm = side ? Wr : Wl;
            int m = k >> 1, isY = k & 1;
            float v = Wm[(4 + 2 * m + isY) * 16 + c];
            if (m == o0[j]) v += Wm[(10 + isY) * 16 + c];
            if (m == o1[j]) v += Wm[(12 + isY) * 16 + c];
            if (m == j)
                v += Wm[(0 + isY) * 16 + c] - Wm[(4 + isY) * 16 + c]
                   - Wm[(6 + isY) * 16 + c] - Wm[(8 + isY) * 16 + c]
                   - Wm[(10 + isY) * 16 + c] - Wm[(12 + isY) * 16 + c];
            lds_wred[side][j][k][c] = v;
        }
    }

    // ---- positions (g-uniform branch) ----
    float px[3], py[3];
    if (g == 0) {
        const float2* ap = reinterpret_cast<const float2*>(agent_pos + b * 6);
#pragma unroll
        for (int j = 0; j < 3; ++j) { px[j] = ap[j].x; py[j] = ap[j].y; }
    } else {
        const float2* lp2 = reinterpret_cast<const float2*>(lm_pos + b * 18);
#pragma unroll
        for (int m = 0; m < 3; ++m) { px[m] = lp2[m].x; py[m] = lp2[m].y; }
    }
    __syncthreads();    // B0: wred ready

    // ---------- phase 1: transform, full 16 channels ----------
    f32x2 xl[3][8], xr[3][8];
    if (g == 0) {
        float xf[3][14];
#pragma unroll
        for (int j = 0; j < 3; ++j) {
            const float2 vel = reinterpret_cast<const float2*>(agent_vel + b * 6)[j];
            const float2* rl = reinterpret_cast<const float2*>(rel_lm + b * 18 + j * 6);
            const float4 op  = reinterpret_cast<const float4*>(other_pos + b * 12)[j];
            xf[j][0] = px[j]; xf[j][1] = py[j];
            xf[j][2] = vel.x; xf[j][3] = vel.y;
            xf[j][4] = rl[0].x; xf[j][5] = rl[0].y;
            xf[j][6] = rl[1].x; xf[j][7] = rl[1].y;
            xf[j][8] = rl[2].x; xf[j][9] = rl[2].y;
            xf[j][10] = op.x; xf[j][11] = op.y; xf[j][12] = op.z; xf[j][13] = op.w;
        }
#pragma unroll
        for (int cc = 0; cc < 8; ++cc) {
            f32x2 vbl = ld2(bl + cc * 2), vbr = ld2(br + cc * 2);
#pragma unroll
            for (int j = 0; j < 3; ++j) { xl[j][cc] = vbl; xr[j][cc] = vbr; }
        }
#pragma unroll
        for (int k = 0; k < 14; ++k) {
#pragma unroll
            for (int cc = 0; cc < 8; ++cc) {
                f32x2 wl2 = ld2(Wl + k * 16 + cc * 2);
                f32x2 wr2 = ld2(Wr + k * 16 + cc * 2);
#pragma unroll
                for (int j = 0; j < 3; ++j) {
                    f32x2 xk = splat2(xf[j][k]);
                    xl[j][cc] = pk_fma(xk, wl2, xl[j][cc]);
                    xr[j][cc] = pk_fma(xk, wr2, xr[j][cc]);
                }
            }
        }
    } else {
        float ps[6] = {px[0], py[0], px[1], py[1], px[2], py[2]};
#pragma unroll
        for (int cc = 0; cc < 8; ++cc) {
            f32x2 vbl = ld2(bl + cc * 2), vbr = ld2(br + cc * 2);
#pragma unroll
            for (int j = 0; j < 3; ++j) { xl[j][cc] = vbl; xr[j][cc] = vbr; }
        }
#pragma unroll
        for (int k = 0; k < 6; ++k) {
            f32x2 pk = splat2(ps[k]);
#pragma unroll
            for (int j = 0; j < 3; ++j) {
#pragma unroll
                for (int cc = 0; cc < 8; ++cc) {
                    xl[j][cc] = pk_fma(pk, ld2(&lds_wred[0][j][k][cc * 2]), xl[j][cc]);
                    xr[j][cc] = pk_fma(pk, ld2(&lds_wred[1][j][k][cc * 2]), xr[j][cc]);
                }
            }
        }
    }

    // ---- pairwise distances + edge geometry (once per sample-graph) ----
    float ax[9], ay[9], ad[9];
    {
        float dx, dy, d01, d02, d12;
        dx = px[0] - px[1]; dy = py[0] - py[1]; d01 = sqrtf(dx * dx + dy * dy);
        dx = px[0] - px[2]; dy = py[0] - py[2]; d02 = sqrtf(dx * dx + dy * dy);
        dx = px[1] - px[2]; dy = py[1] - py[2]; d12 = sqrtf(dx * dx + dy * dy);
#pragma unroll
        for (int i = 0; i < 3; ++i) {
#pragma unroll
            for (int j = 0; j < 3; ++j) {
                int e = j * 3 + i;
                if (i == j) {
                    const int a = o0[i], c2 = o1[i];
                    ax[e] = 0.5f * (px[a] + px[c2]) - px[i];
                    ay[e] = 0.5f * (py[a] + py[c2]) - py[i];
                    const float dA = (i == 0) ? d01 : ((i == 1) ? d01 : d02);
                    const float dB = (i == 0) ? d02 : ((i == 1) ? d12 : d12);
                    ad[e] = 0.5f * (dA + dB);
                } else {
                    ax[e] = px[j] - px[i];
                    ay[e] = py[j] - py[i];
                    ad[e] = ((i == 0 && j == 1) || (i == 1 && j == 0)) ? d01
                          : ((i == 0 && j == 2) || (i == 2 && j == 0)) ? d02 : d12;
                }
            }
        }
    }

    // ---- full logits (no exchange needed), edge-outer over 16 ch ----
    float lg[9];
#pragma unroll
    for (int j = 0; j < 3; ++j) {
#pragma unroll
        for (int i = 0; i < 3; ++i) {
            int e = j * 3 + i;
            f32x2 vax = splat2(ax[e]), vay = splat2(ay[e]), vad = splat2(ad[e]);
            f32x2 acc = {0.f, 0.f};
#pragma unroll
            for (int cc = 0; cc < 8; ++cc) {
                f32x2 gg = xl[j][cc] + xr[i][cc];
                gg = pk_fma(vax, ld2(We + cc * 2), gg);
                gg = pk_fma(vay, ld2(We + 16 + cc * 2), gg);
                gg = pk_fma(vad, ld2(We + 32 + cc * 2), gg);
                f32x2 lk = pk_max(gg, gg * splat2(NEG_SLOPE));
                acc = pk_fma(lk, ld2(att + cc * 2), acc);
            }
            lg[e] = acc.x + acc.y;
        }
    }

    // ---- softmax per target (once per sample-graph) + pooled relu-sum ----
    f32x2 hs[8] = {{0,0},{0,0},{0,0},{0,0},{0,0},{0,0},{0,0},{0,0}};
    const f32x2 zero2 = {0.f, 0.f};
#pragma unroll
    for (int i = 0; i < 3; ++i) {
        float e0 = __expf(lg[i]);
        float e1 = __expf(lg[3 + i]);
        float e2 = __expf(lg[6 + i]);
        float inv = __builtin_amdgcn_rcpf(e0 + e1 + e2);
        f32x2 a0 = splat2(e0 * inv), a1 = splat2(e1 * inv), a2 = splat2(e2 * inv);
#pragma unroll
        for (int cc = 0; cc < 8; ++cc) {
            f32x2 v = pk_fma(a0, xl[0][cc],
                      pk_fma(a1, xl[1][cc],
                      pk_fma(a2, xl[2][cc], ld2(bias + cc * 2))));
            hs[cc] += pk_max(v, zero2);
        }
    }

    // ---- publish pooled h (16 ch = 2x bf16x8) ----
    {
        bf16x8 hv0, hv1;
#pragma unroll
        for (int cc = 0; cc < 4; ++cc) {
            hv0[cc * 2 + 0] = (__bf16)hs[cc].x;     hv0[cc * 2 + 1] = (__bf16)hs[cc].y;
            hv1[cc * 2 + 0] = (__bf16)hs[4 + cc].x; hv1[cc * 2 + 1] = (__bf16)hs[4 + cc].y;
        }
        *reinterpret_cast<bf16x8*>(&lds_h[sRow][g * 16])     = hv0;
        *reinterpret_cast<bf16x8*>(&lds_h[sRow][g * 16 + 8]) = hv1;
    }

    // ---- fragment + bias loads (deferred: keep GAT-phase VGPR pressure low) ----
    bf16x8 w1f[8], w2f[8];
#pragma unroll
    for (int n = 0; n < 8; ++n) w1f[n] = W1F[(n << 6) | lane];
#pragma unroll
    for (int t = 0; t < 8; ++t) w2f[t] = W2F[(t << 6) | lane];
    float b1v[8], b2v[2];
#pragma unroll
    for (int n = 0; n < 8; ++n) b1v[n] = b1[n * 16 + l15];
#pragma unroll
    for (int nn = 0; nn < 2; ++nn) b2v[nn] = b2[nn * 16 + l15];

    __syncthreads();    // B2: h ready

    // ---------- phase 2: MLP via MFMA 16x16x32 bf16 (validated R8), 2 tiles/wave ----------
#pragma unroll
    for (int tt = 0; tt < 2; ++tt) {
        const int tile = wu * 2 + tt;          // 0..7
        const int row0 = tile * 16;

        bf16x8 a1 = *reinterpret_cast<const bf16x8*>(&lds_h[row0 + l15][l4 * 8]);
        f32x4 acc[8];
#pragma unroll
        for (int n = 0; n < 8; ++n)
            acc[n] = __builtin_amdgcn_mfma_f32_16x16x32_bf16(a1, w1f[n], zero4, 0, 0, 0);
#pragma unroll
        for (int r = 0; r < 4; ++r) {
            bf16x8 zv;
#pragma unroll
            for (int n = 0; n < 8; ++n) zv[n] = (__bf16)relu_f(acc[n][r] + b1v[n]);
            *reinterpret_cast<bf16x8*>(&lds_z[wu][l4 * 4 + r][l15 * 8]) = zv;
        }

        f32x4 o2[2] = {zero4, zero4};
#pragma unroll
        for (int ks = 0; ks < 4; ++ks) {
            bf16x8 a2 = *reinterpret_cast<const bf16x8*>(&lds_z[wu][l15][ks * 32 + l4 * 8]);
#pragma unroll
            for (int nn = 0; nn < 2; ++nn)
                o2[nn] = __builtin_amdgcn_mfma_f32_16x16x32_bf16(a2, w2f[ks * 2 + nn], o2[nn], 0, 0, 0);
        }

#pragma unroll
        for (int nn = 0; nn < 2; ++nn) {
#pragma unroll
            for (int r = 0; r < 4; ++r) {
                int row = blk + row0 + l4 * 4 + r;
                if (row < Btot)
                    out[(size_t)row * 32 + nn * 16 + l15] = o2[nn][r] + b2v[nn];
            }
        }
    }
}

extern "C" void kernel_launch(void* const* d_in, const int* in_sizes, int n_in,
                              void* d_out, int out_size, void* d_ws, size_t ws_size,
                              hipStream_t stream) {
    const float* agent_pos = (const float*)d_in[0];
    const float* agent_vel = (const float*)d_in[1];
    const float* rel_lm    = (const float*)d_in[2];
    const float* other_pos = (const float*)d_in[3];
    const float* lm_pos    = (const float*)d_in[4];
    const float* Wl   = (const float*)d_in[5];
    const float* bl   = (const float*)d_in[6];
    const float* Wr   = (const float*)d_in[7];
    const float* br   = (const float*)d_in[8];
    const float* We   = (const float*)d_in[9];
    const float* att  = (const float*)d_in[10];
    const float* bias = (const float*)d_in[11];
    const float* W1   = (const float*)d_in[12];
    const float* b1   = (const float*)d_in[13];
    const float* W2   = (const float*)d_in[14];
    const float* b2   = (const float*)d_in[15];
    float* out = (float*)d_out;

    __bf16* W1F = (__bf16*)d_ws;                   // 8 KB
    __bf16* W2F = (__bf16*)((char*)d_ws + 8192);   // 8 KB

    prep_weights<<<32, 256, 0, stream>>>(W1, W2, W1F, W2F);

    int B = in_sizes[0] / 6;                  // agent_pos is [B,3,2]
    int grid = (B + 127) / 128;
    scl_fused_kernel<<<grid, 256, 0, stream>>>(
        agent_pos, agent_vel, rel_lm, other_pos, lm_pos,
        Wl, bl, Wr, br, We, att, bias,
        (const bf16x8*)W1F, b1, (const bf16x8*)W2F, b2, out, B);
}

// Round 19
// 33.378 us; speedup vs baseline: 1.6685x; 1.0313x over previous
//
#include <hip/hip_runtime.h>

#define NEG_SLOPE 0.2f

typedef __bf16 bf16x8 __attribute__((ext_vector_type(8)));
typedef float  f32x4  __attribute__((ext_vector_type(4)));
typedef float  f32x2  __attribute__((ext_vector_type(2)));

__device__ __forceinline__ float relu_f(float v) { return v > 0.f ? v : 0.f; }
__device__ __forceinline__ f32x2 pk_fma(f32x2 a, f32x2 b, f32x2 c) { return __builtin_elementwise_fma(a, b, c); }
__device__ __forceinline__ f32x2 pk_max(f32x2 a, f32x2 b) { return __builtin_elementwise_max(a, b); }
__device__ __forceinline__ f32x2 splat2(float s) { f32x2 r = {s, s}; return r; }
__device__ __forceinline__ f32x2 ld2(const float* p) { return *reinterpret_cast<const f32x2*>(p); }

// ---------------- prep: W1/W2 fragments + WRED into d_ws ----------------
// W1F/W2F: validated R7-R18 MLP fragments.
// WRED (moved from per-block phase 0): g=1 reduced transform. Landmark feats are
// linear in the 6 position scalars -> x@W == p@WRED (exact fp32 algebra).
// Layout WRED[((side*3+j)*6+k)*16+c], side 0=l 1=r.
__global__ __launch_bounds__(256)
void prep_weights(const float* __restrict__ Wl, const float* __restrict__ Wr,
                  const float* __restrict__ W1, const float* __restrict__ W2,
                  __bf16* __restrict__ W1F, __bf16* __restrict__ W2F,
                  float* __restrict__ WRED)
{
    const int o0[3] = {1, 0, 0};
    const int o1[3] = {2, 2, 1};
    int idx = blockIdx.x * 256 + threadIdx.x;   // 0..9215
    if (idx < 4096) {
        int e = idx; int j = e & 7, l = (e >> 3) & 63, t = e >> 9;
        int l15 = l & 15, l4 = l >> 4;
        W1F[e] = (__bf16)W1[(l4 * 8 + j) * 128 + t * 16 + l15];
    } else if (idx < 8192) {
        int e = idx - 4096; int j = e & 7, l = (e >> 3) & 63, t = e >> 9;
        int l15 = l & 15, l4 = l >> 4;
        int ks = t >> 1, nn = t & 1;
        W2F[e] = (__bf16)W2[(j * 16 + ks * 4 + l4) * 32 + nn * 16 + l15];
    } else if (idx < 8768) {
        int e = idx - 8192;                 // 0..575
        int c = e & 15;
        int r16 = e >> 4;                   // (side*3+j)*6+k
        int k = r16 % 6, sj = r16 / 6, j = sj % 3, side = sj / 3;
        const float* Wm = side ? Wr : Wl;
        int m = k >> 1, isY = k & 1;
        float v = Wm[(4 + 2 * m + isY) * 16 + c];
        if (m == o0[j]) v += Wm[(10 + isY) * 16 + c];
        if (m == o1[j]) v += Wm[(12 + isY) * 16 + c];
        if (m == j)
            v += Wm[(0 + isY) * 16 + c] - Wm[(4 + isY) * 16 + c]
               - Wm[(6 + isY) * 16 + c] - Wm[(8 + isY) * 16 + c]
               - Wm[(10 + isY) * 16 + c] - Wm[(12 + isY) * 16 + c];
        WRED[e] = v;
    }
}

// ============ Fused kernel: 16-channel waves, ONE barrier ============
// Block = 256 threads = 4 waves, 128 samples. wave w -> g = w&1 (graph),
// sg = w>>1 (sample group). Each thread: one (sample, graph), ALL 16 channels.
// R19 vs R18 (validated): WRED precomputed in prep (sample-independent) ->
// no per-block wred compute, no lds_wred, and barrier B0 DELETED. g1 reads
// WRED at compile-time-uniform offsets -> scalar s_loads. One barrier (B2).
// LDS: h[128][40] 10240 + z[4][16][136] 17408 = 27648 B.
__global__ __launch_bounds__(256)
void scl_fused_kernel(
    const float* __restrict__ agent_pos, const float* __restrict__ agent_vel,
    const float* __restrict__ rel_lm, const float* __restrict__ other_pos,
    const float* __restrict__ lm_pos,
    const float* __restrict__ Wl, const float* __restrict__ bl,
    const float* __restrict__ Wr, const float* __restrict__ br,
    const float* __restrict__ We, const float* __restrict__ att,
    const float* __restrict__ bias,
    const bf16x8* __restrict__ W1F, const float* __restrict__ b1,
    const bf16x8* __restrict__ W2F, const float* __restrict__ b2,
    const float* __restrict__ WRED,
    float* __restrict__ out, int Btot)
{
    __shared__ alignas(16) __bf16 lds_h[128][40];          // pooled GAT out (128 samples)
    __shared__ alignas(16) __bf16 lds_z[4][16][136];       // per-wave z (R8 layout)

    const int tid  = threadIdx.x;
    const int lane = tid & 63;
    const int w    = tid >> 6;
    const int g    = __builtin_amdgcn_readfirstlane(w & 1);
    const int sg   = __builtin_amdgcn_readfirstlane(w >> 1);
    const int wu   = __builtin_amdgcn_readfirstlane(w);
    const int l15  = lane & 15;
    const int l4   = lane >> 4;

    const int blk  = blockIdx.x * 128;
    const int sRow = sg * 64 + lane;            // row in lds_h
    int b = blk + sRow;
    if (b >= Btot) b = Btot - 1;                // clamp reads; barrier stays uniform

    const int o0[3] = {1, 0, 0};
    const int o1[3] = {2, 2, 1};
    const f32x4 zero4 = {0.f, 0.f, 0.f, 0.f};

    // ---- positions (g-uniform branch) + early g0 feature loads ----
    float px[3], py[3];
    float xf[3][14];
    if (g == 0) {
        const float2* ap = reinterpret_cast<const float2*>(agent_pos + b * 6);
#pragma unroll
        for (int j = 0; j < 3; ++j) { px[j] = ap[j].x; py[j] = ap[j].y; }
#pragma unroll
        for (int j = 0; j < 3; ++j) {
            const float2 vel = reinterpret_cast<const float2*>(agent_vel + b * 6)[j];
            const float2* rl = reinterpret_cast<const float2*>(rel_lm + b * 18 + j * 6);
            const float4 op  = reinterpret_cast<const float4*>(other_pos + b * 12)[j];
            xf[j][0] = px[j]; xf[j][1] = py[j];
            xf[j][2] = vel.x; xf[j][3] = vel.y;
            xf[j][4] = rl[0].x; xf[j][5] = rl[0].y;
            xf[j][6] = rl[1].x; xf[j][7] = rl[1].y;
            xf[j][8] = rl[2].x; xf[j][9] = rl[2].y;
            xf[j][10] = op.x; xf[j][11] = op.y; xf[j][12] = op.z; xf[j][13] = op.w;
        }
    } else {
        const float2* lp2 = reinterpret_cast<const float2*>(lm_pos + b * 18);
#pragma unroll
        for (int m = 0; m < 3; ++m) { px[m] = lp2[m].x; py[m] = lp2[m].y; }
    }

    // ---------- phase 1: transform, full 16 channels ----------
    f32x2 xl[3][8], xr[3][8];
    if (g == 0) {
#pragma unroll
        for (int cc = 0; cc < 8; ++cc) {
            f32x2 vbl = ld2(bl + cc * 2), vbr = ld2(br + cc * 2);
#pragma unroll
            for (int j = 0; j < 3; ++j) { xl[j][cc] = vbl; xr[j][cc] = vbr; }
        }
#pragma unroll
        for (int k = 0; k < 14; ++k) {
#pragma unroll
            for (int cc = 0; cc < 8; ++cc) {
                f32x2 wl2 = ld2(Wl + k * 16 + cc * 2);
                f32x2 wr2 = ld2(Wr + k * 16 + cc * 2);
#pragma unroll
                for (int j = 0; j < 3; ++j) {
                    f32x2 xk = splat2(xf[j][k]);
                    xl[j][cc] = pk_fma(xk, wl2, xl[j][cc]);
                    xr[j][cc] = pk_fma(xk, wr2, xr[j][cc]);
                }
            }
        }
    } else {
        float ps[6] = {px[0], py[0], px[1], py[1], px[2], py[2]};
#pragma unroll
        for (int cc = 0; cc < 8; ++cc) {
            f32x2 vbl = ld2(bl + cc * 2), vbr = ld2(br + cc * 2);
#pragma unroll
            for (int j = 0; j < 3; ++j) { xl[j][cc] = vbl; xr[j][cc] = vbr; }
        }
#pragma unroll
        for (int k = 0; k < 6; ++k) {
            f32x2 pk = splat2(ps[k]);
#pragma unroll
            for (int j = 0; j < 3; ++j) {
                const float* wl0 = WRED + ((0 * 3 + j) * 6 + k) * 16;
                const float* wr0 = WRED + ((1 * 3 + j) * 6 + k) * 16;
#pragma unroll
                for (int cc = 0; cc < 8; ++cc) {
                    xl[j][cc] = pk_fma(pk, ld2(wl0 + cc * 2), xl[j][cc]);
                    xr[j][cc] = pk_fma(pk, ld2(wr0 + cc * 2), xr[j][cc]);
                }
            }
        }
    }

    // ---- pairwise distances + edge geometry (once per sample-graph) ----
    float ax[9], ay[9], ad[9];
    {
        float dx, dy, d01, d02, d12;
        dx = px[0] - px[1]; dy = py[0] - py[1]; d01 = sqrtf(dx * dx + dy * dy);
        dx = px[0] - px[2]; dy = py[0] - py[2]; d02 = sqrtf(dx * dx + dy * dy);
        dx = px[1] - px[2]; dy = py[1] - py[2]; d12 = sqrtf(dx * dx + dy * dy);
#pragma unroll
        for (int i = 0; i < 3; ++i) {
#pragma unroll
            for (int j = 0; j < 3; ++j) {
                int e = j * 3 + i;
                if (i == j) {
                    const int a = o0[i], c2 = o1[i];
                    ax[e] = 0.5f * (px[a] + px[c2]) - px[i];
                    ay[e] = 0.5f * (py[a] + py[c2]) - py[i];
                    const float dA = (i == 0) ? d01 : ((i == 1) ? d01 : d02);
                    const float dB = (i == 0) ? d02 : ((i == 1) ? d12 : d12);
                    ad[e] = 0.5f * (dA + dB);
                } else {
                    ax[e] = px[j] - px[i];
                    ay[e] = py[j] - py[i];
                    ad[e] = ((i == 0 && j == 1) || (i == 1 && j == 0)) ? d01
                          : ((i == 0 && j == 2) || (i == 2 && j == 0)) ? d02 : d12;
                }
            }
        }
    }

    // ---- full logits (no exchange), edge-outer over 16 ch ----
    float lg[9];
#pragma unroll
    for (int j = 0; j < 3; ++j) {
#pragma unroll
        for (int i = 0; i < 3; ++i) {
            int e = j * 3 + i;
            f32x2 vax = splat2(ax[e]), vay = splat2(ay[e]), vad = splat2(ad[e]);
            f32x2 acc = {0.f, 0.f};
#pragma unroll
            for (int cc = 0; cc < 8; ++cc) {
                f32x2 gg = xl[j][cc] + xr[i][cc];
                gg = pk_fma(vax, ld2(We + cc * 2), gg);
                gg = pk_fma(vay, ld2(We + 16 + cc * 2), gg);
                gg = pk_fma(vad, ld2(We + 32 + cc * 2), gg);
                f32x2 lk = pk_max(gg, gg * splat2(NEG_SLOPE));
                acc = pk_fma(lk, ld2(att + cc * 2), acc);
            }
            lg[e] = acc.x + acc.y;
        }
    }

    // ---- softmax per target (once per sample-graph) + pooled relu-sum ----
    f32x2 hs[8] = {{0,0},{0,0},{0,0},{0,0},{0,0},{0,0},{0,0},{0,0}};
    const f32x2 zero2 = {0.f, 0.f};
#pragma unroll
    for (int i = 0; i < 3; ++i) {
        float e0 = __expf(lg[i]);
        float e1 = __expf(lg[3 + i]);
        float e2 = __expf(lg[6 + i]);
        float inv = __builtin_amdgcn_rcpf(e0 + e1 + e2);
        f32x2 a0 = splat2(e0 * inv), a1 = splat2(e1 * inv), a2 = splat2(e2 * inv);
#pragma unroll
        for (int cc = 0; cc < 8; ++cc) {
            f32x2 v = pk_fma(a0, xl[0][cc],
                      pk_fma(a1, xl[1][cc],
                      pk_fma(a2, xl[2][cc], ld2(bias + cc * 2))));
            hs[cc] += pk_max(v, zero2);
        }
    }

    // ---- publish pooled h (16 ch = 2x bf16x8) ----
    {
        bf16x8 hv0, hv1;
#pragma unroll
        for (int cc = 0; cc < 4; ++cc) {
            hv0[cc * 2 + 0] = (__bf16)hs[cc].x;     hv0[cc * 2 + 1] = (__bf16)hs[cc].y;
            hv1[cc * 2 + 0] = (__bf16)hs[4 + cc].x; hv1[cc * 2 + 1] = (__bf16)hs[4 + cc].y;
        }
        *reinterpret_cast<bf16x8*>(&lds_h[sRow][g * 16])     = hv0;
        *reinterpret_cast<bf16x8*>(&lds_h[sRow][g * 16 + 8]) = hv1;
    }

    // ---- fragment + bias loads (deferred: GAT-phase pressure) ----
    bf16x8 w1f[8], w2f[8];
#pragma unroll
    for (int n = 0; n < 8; ++n) w1f[n] = W1F[(n << 6) | lane];
#pragma unroll
    for (int t = 0; t < 8; ++t) w2f[t] = W2F[(t << 6) | lane];
    float b1v[8], b2v[2];
#pragma unroll
    for (int n = 0; n < 8; ++n) b1v[n] = b1[n * 16 + l15];
#pragma unroll
    for (int nn = 0; nn < 2; ++nn) b2v[nn] = b2[nn * 16 + l15];

    __syncthreads();    // B2: h ready (the ONLY barrier)

    // ---------- phase 2: MLP via MFMA 16x16x32 bf16 (validated R8), 2 tiles/wave ----------
#pragma unroll
    for (int tt = 0; tt < 2; ++tt) {
        const int tile = wu * 2 + tt;          // 0..7
        const int row0 = tile * 16;

        bf16x8 a1 = *reinterpret_cast<const bf16x8*>(&lds_h[row0 + l15][l4 * 8]);
        f32x4 acc[8];
#pragma unroll
        for (int n = 0; n < 8; ++n)
            acc[n] = __builtin_amdgcn_mfma_f32_16x16x32_bf16(a1, w1f[n], zero4, 0, 0, 0);
#pragma unroll
        for (int r = 0; r < 4; ++r) {
            bf16x8 zv;
#pragma unroll
            for (int n = 0; n < 8; ++n) zv[n] = (__bf16)relu_f(acc[n][r] + b1v[n]);
            *reinterpret_cast<bf16x8*>(&lds_z[wu][l4 * 4 + r][l15 * 8]) = zv;
        }

        f32x4 o2[2] = {zero4, zero4};
#pragma unroll
        for (int ks = 0; ks < 4; ++ks) {
            bf16x8 a2 = *reinterpret_cast<const bf16x8*>(&lds_z[wu][l15][ks * 32 + l4 * 8]);
#pragma unroll
            for (int nn = 0; nn < 2; ++nn)
                o2[nn] = __builtin_amdgcn_mfma_f32_16x16x32_bf16(a2, w2f[ks * 2 + nn], o2[nn], 0, 0, 0);
        }

#pragma unroll
        for (int nn = 0; nn < 2; ++nn) {
#pragma unroll
            for (int r = 0; r < 4; ++r) {
                int row = blk + row0 + l4 * 4 + r;
                if (row < Btot)
                    out[(size_t)row * 32 + nn * 16 + l15] = o2[nn][r] + b2v[nn];
            }
        }
    }
}

extern "C" void kernel_launch(void* const* d_in, const int* in_sizes, int n_in,
                              void* d_out, int out_size, void* d_ws, size_t ws_size,
                              hipStream_t stream) {
    const float* agent_pos = (const float*)d_in[0];
    const float* agent_vel = (const float*)d_in[1];
    const float* rel_lm    = (const float*)d_in[2];
    const float* other_pos = (const float*)d_in[3];
    const float* lm_pos    = (const float*)d_in[4];
    const float* Wl   = (const float*)d_in[5];
    const float* bl   = (const float*)d_in[6];
    const float* Wr   = (const float*)d_in[7];
    const float* br   = (const float*)d_in[8];
    const float* We   = (const float*)d_in[9];
    const float* att  = (const float*)d_in[10];
    const float* bias = (const float*)d_in[11];
    const float* W1   = (const float*)d_in[12];
    const float* b1   = (const float*)d_in[13];
    const float* W2   = (const float*)d_in[14];
    const float* b2   = (const float*)d_in[15];
    float* out = (float*)d_out;

    __bf16* W1F  = (__bf16*)d_ws;                    // 8 KB
    __bf16* W2F  = (__bf16*)((char*)d_ws + 8192);    // 8 KB
    float*  WRED = (float*)((char*)d_ws + 16384);    // 2304 B

    prep_weights<<<36, 256, 0, stream>>>(Wl, Wr, W1, W2, W1F, W2F, WRED);

    int B = in_sizes[0] / 6;                  // agent_pos is [B,3,2]
    int grid = (B + 127) / 128;
    scl_fused_kernel<<<grid, 256, 0, stream>>>(
        agent_pos, agent_vel, rel_lm, other_pos, lm_pos,
        Wl, bl, Wr, br, We, att, bias,
        (const bf16x8*)W1F, b1, (const bf16x8*)W2F, b2, WRED, out, B);
}

// Round 20
// 30.207 us; speedup vs baseline: 1.8437x; 1.1050x over previous
//
#include <hip/hip_runtime.h>

#define NEG_SLOPE 0.2f

typedef __bf16 bf16x8 __attribute__((ext_vector_type(8)));
typedef float  f32x4  __attribute__((ext_vector_type(4)));
typedef float  f32x2  __attribute__((ext_vector_type(2)));

__device__ __forceinline__ float relu_f(float v) { return v > 0.f ? v : 0.f; }
__device__ __forceinline__ f32x2 pk_fma(f32x2 a, f32x2 b, f32x2 c) { return __builtin_elementwise_fma(a, b, c); }
__device__ __forceinline__ f32x2 pk_max(f32x2 a, f32x2 b) { return __builtin_elementwise_max(a, b); }
__device__ __forceinline__ f32x2 splat2(float s) { f32x2 r = {s, s}; return r; }
__device__ __forceinline__ f32x2 ld2(const float* p) { return *reinterpret_cast<const f32x2*>(p); }

// ============ SINGLE fused kernel: GAT + MLP. No prep, no workspace. ============
// Block = 256 threads = 4 waves, 128 samples. wave w -> g = w&1 (graph),
// sg = w>>1 (sample group). Each thread: one (sample, graph), ALL 16 channels
// as 8x f32x2 (R18 structure, validated).
// R20 vs R19: prep kernel DELETED. (1) W1/W2 MFMA B-fragments loaded directly
// with per-lane strided loads (R6==R7 proved this matches pre-swizzled speed;
// L2-hot 16KB constant). (2) WRED dropped: g1 landmark features built directly
// (R9-validated), unifying both graphs into ONE transform loop.
// Barriers: ONE (__syncthreads before MLP). LDS: h 10240 + z 17408 = 27648 B.
__global__ __launch_bounds__(256)
void scl_fused_kernel(
    const float* __restrict__ agent_pos, const float* __restrict__ agent_vel,
    const float* __restrict__ rel_lm, const float* __restrict__ other_pos,
    const float* __restrict__ lm_pos,
    const float* __restrict__ Wl, const float* __restrict__ bl,
    const float* __restrict__ Wr, const float* __restrict__ br,
    const float* __restrict__ We, const float* __restrict__ att,
    const float* __restrict__ bias,
    const float* __restrict__ W1, const float* __restrict__ b1,
    const float* __restrict__ W2, const float* __restrict__ b2,
    float* __restrict__ out, int Btot)
{
    __shared__ alignas(16) __bf16 lds_h[128][40];          // pooled GAT out (128 samples)
    __shared__ alignas(16) __bf16 lds_z[4][16][136];       // per-wave z (R8 layout)

    const int tid  = threadIdx.x;
    const int lane = tid & 63;
    const int w    = tid >> 6;
    const int g    = __builtin_amdgcn_readfirstlane(w & 1);
    const int sg   = __builtin_amdgcn_readfirstlane(w >> 1);
    const int wu   = __builtin_amdgcn_readfirstlane(w);
    const int l15  = lane & 15;
    const int l4   = lane >> 4;

    const int blk  = blockIdx.x * 128;
    const int sRow = sg * 64 + lane;            // row in lds_h
    int b = blk + sRow;
    if (b >= Btot) b = Btot - 1;                // clamp reads; barrier stays uniform

    const int o0[3] = {1, 0, 0};
    const int o1[3] = {2, 2, 1};
    const f32x4 zero4 = {0.f, 0.f, 0.f, 0.f};

    // ---- positions + 14-feature build (g-uniform branch; then unified math) ----
    float px[3], py[3];
    float xf[3][14];
    if (g == 0) {
        const float2* ap = reinterpret_cast<const float2*>(agent_pos + b * 6);
#pragma unroll
        for (int j = 0; j < 3; ++j) { px[j] = ap[j].x; py[j] = ap[j].y; }
#pragma unroll
        for (int j = 0; j < 3; ++j) {
            const float2 vel = reinterpret_cast<const float2*>(agent_vel + b * 6)[j];
            const float2* rl = reinterpret_cast<const float2*>(rel_lm + b * 18 + j * 6);
            const float4 op  = reinterpret_cast<const float4*>(other_pos + b * 12)[j];
            xf[j][0] = px[j]; xf[j][1] = py[j];
            xf[j][2] = vel.x; xf[j][3] = vel.y;
            xf[j][4] = rl[0].x; xf[j][5] = rl[0].y;
            xf[j][6] = rl[1].x; xf[j][7] = rl[1].y;
            xf[j][8] = rl[2].x; xf[j][9] = rl[2].y;
            xf[j][10] = op.x; xf[j][11] = op.y; xf[j][12] = op.z; xf[j][13] = op.w;
        }
    } else {
        const float2* lp2 = reinterpret_cast<const float2*>(lm_pos + b * 18);
#pragma unroll
        for (int m = 0; m < 3; ++m) { px[m] = lp2[m].x; py[m] = lp2[m].y; }
#pragma unroll
        for (int j = 0; j < 3; ++j) {
            xf[j][0] = px[j]; xf[j][1] = py[j];
            xf[j][2] = 0.f;   xf[j][3] = 0.f;
#pragma unroll
            for (int m = 0; m < 3; ++m) {
                xf[j][4 + 2 * m] = px[m] - px[j];
                xf[j][5 + 2 * m] = py[m] - py[j];
            }
            const int a = o0[j], c2 = o1[j];
            xf[j][10] = px[a]  - px[j]; xf[j][11] = py[a]  - py[j];
            xf[j][12] = px[c2] - px[j]; xf[j][13] = py[c2] - py[j];
        }
    }

    // ---------- phase 1: transform, full 16 channels (unified for both graphs) ----------
    f32x2 xl[3][8], xr[3][8];
#pragma unroll
    for (int cc = 0; cc < 8; ++cc) {
        f32x2 vbl = ld2(bl + cc * 2), vbr = ld2(br + cc * 2);
#pragma unroll
        for (int j = 0; j < 3; ++j) { xl[j][cc] = vbl; xr[j][cc] = vbr; }
    }
#pragma unroll
    for (int k = 0; k < 14; ++k) {
#pragma unroll
        for (int cc = 0; cc < 8; ++cc) {
            f32x2 wl2 = ld2(Wl + k * 16 + cc * 2);
            f32x2 wr2 = ld2(Wr + k * 16 + cc * 2);
#pragma unroll
            for (int j = 0; j < 3; ++j) {
                f32x2 xk = splat2(xf[j][k]);
                xl[j][cc] = pk_fma(xk, wl2, xl[j][cc]);
                xr[j][cc] = pk_fma(xk, wr2, xr[j][cc]);
            }
        }
    }

    // ---- pairwise distances + edge geometry (once per sample-graph) ----
    float ax[9], ay[9], ad[9];
    {
        float dx, dy, d01, d02, d12;
        dx = px[0] - px[1]; dy = py[0] - py[1]; d01 = sqrtf(dx * dx + dy * dy);
        dx = px[0] - px[2]; dy = py[0] - py[2]; d02 = sqrtf(dx * dx + dy * dy);
        dx = px[1] - px[2]; dy = py[1] - py[2]; d12 = sqrtf(dx * dx + dy * dy);
#pragma unroll
        for (int i = 0; i < 3; ++i) {
#pragma unroll
            for (int j = 0; j < 3; ++j) {
                int e = j * 3 + i;
                if (i == j) {
                    const int a = o0[i], c2 = o1[i];
                    ax[e] = 0.5f * (px[a] + px[c2]) - px[i];
                    ay[e] = 0.5f * (py[a] + py[c2]) - py[i];
                    const float dA = (i == 0) ? d01 : ((i == 1) ? d01 : d02);
                    const float dB = (i == 0) ? d02 : ((i == 1) ? d12 : d12);
                    ad[e] = 0.5f * (dA + dB);
                } else {
                    ax[e] = px[j] - px[i];
                    ay[e] = py[j] - py[i];
                    ad[e] = ((i == 0 && j == 1) || (i == 1 && j == 0)) ? d01
                          : ((i == 0 && j == 2) || (i == 2 && j == 0)) ? d02 : d12;
                }
            }
        }
    }

    // ---- full logits (no exchange), edge-outer over 16 ch ----
    float lg[9];
#pragma unroll
    for (int j = 0; j < 3; ++j) {
#pragma unroll
        for (int i = 0; i < 3; ++i) {
            int e = j * 3 + i;
            f32x2 vax = splat2(ax[e]), vay = splat2(ay[e]), vad = splat2(ad[e]);
            f32x2 acc = {0.f, 0.f};
#pragma unroll
            for (int cc = 0; cc < 8; ++cc) {
                f32x2 gg = xl[j][cc] + xr[i][cc];
                gg = pk_fma(vax, ld2(We + cc * 2), gg);
                gg = pk_fma(vay, ld2(We + 16 + cc * 2), gg);
                gg = pk_fma(vad, ld2(We + 32 + cc * 2), gg);
                f32x2 lk = pk_max(gg, gg * splat2(NEG_SLOPE));
                acc = pk_fma(lk, ld2(att + cc * 2), acc);
            }
            lg[e] = acc.x + acc.y;
        }
    }

    // ---- softmax per target (once per sample-graph) + pooled relu-sum ----
    f32x2 hs[8] = {{0,0},{0,0},{0,0},{0,0},{0,0},{0,0},{0,0},{0,0}};
    const f32x2 zero2 = {0.f, 0.f};
#pragma unroll
    for (int i = 0; i < 3; ++i) {
        float e0 = __expf(lg[i]);
        float e1 = __expf(lg[3 + i]);
        float e2 = __expf(lg[6 + i]);
        float inv = __builtin_amdgcn_rcpf(e0 + e1 + e2);
        f32x2 a0 = splat2(e0 * inv), a1 = splat2(e1 * inv), a2 = splat2(e2 * inv);
#pragma unroll
        for (int cc = 0; cc < 8; ++cc) {
            f32x2 v = pk_fma(a0, xl[0][cc],
                      pk_fma(a1, xl[1][cc],
                      pk_fma(a2, xl[2][cc], ld2(bias + cc * 2))));
            hs[cc] += pk_max(v, zero2);
        }
    }

    // ---- publish pooled h (16 ch = 2x bf16x8) ----
    {
        bf16x8 hv0, hv1;
#pragma unroll
        for (int cc = 0; cc < 4; ++cc) {
            hv0[cc * 2 + 0] = (__bf16)hs[cc].x;     hv0[cc * 2 + 1] = (__bf16)hs[cc].y;
            hv1[cc * 2 + 0] = (__bf16)hs[4 + cc].x; hv1[cc * 2 + 1] = (__bf16)hs[4 + cc].y;
        }
        *reinterpret_cast<bf16x8*>(&lds_h[sRow][g * 16])     = hv0;
        *reinterpret_cast<bf16x8*>(&lds_h[sRow][g * 16 + 8]) = hv1;
    }

    // ---- MFMA B-fragments: DIRECT strided loads from W1/W2 (R6==R7 validated).
    //      Index math identical to prep_weights (incl. W2 z-permutation).
    bf16x8 w1f[8], w2f[8];
#pragma unroll
    for (int n = 0; n < 8; ++n) {
        const float* Wcol = W1 + (l4 * 8) * 128 + n * 16 + l15;
#pragma unroll
        for (int j = 0; j < 8; ++j) w1f[n][j] = (__bf16)Wcol[j * 128];
    }
#pragma unroll
    for (int t = 0; t < 8; ++t) {
        const int ks = t >> 1, nn = t & 1;
        const float* Wcol = W2 + (ks * 4 + l4) * 32 + nn * 16 + l15;
#pragma unroll
        for (int j = 0; j < 8; ++j) w2f[t][j] = (__bf16)Wcol[j * 16 * 32];
    }
    float b1v[8], b2v[2];
#pragma unroll
    for (int n = 0; n < 8; ++n) b1v[n] = b1[n * 16 + l15];
#pragma unroll
    for (int nn = 0; nn < 2; ++nn) b2v[nn] = b2[nn * 16 + l15];

    __syncthreads();    // the ONLY barrier: h ready

    // ---------- phase 2: MLP via MFMA 16x16x32 bf16 (validated R8), 2 tiles/wave ----------
#pragma unroll
    for (int tt = 0; tt < 2; ++tt) {
        const int tile = wu * 2 + tt;          // 0..7
        const int row0 = tile * 16;

        bf16x8 a1 = *reinterpret_cast<const bf16x8*>(&lds_h[row0 + l15][l4 * 8]);
        f32x4 acc[8];
#pragma unroll
        for (int n = 0; n < 8; ++n)
            acc[n] = __builtin_amdgcn_mfma_f32_16x16x32_bf16(a1, w1f[n], zero4, 0, 0, 0);
#pragma unroll
        for (int r = 0; r < 4; ++r) {
            bf16x8 zv;
#pragma unroll
            for (int n = 0; n < 8; ++n) zv[n] = (__bf16)relu_f(acc[n][r] + b1v[n]);
            *reinterpret_cast<bf16x8*>(&lds_z[wu][l4 * 4 + r][l15 * 8]) = zv;
        }

        f32x4 o2[2] = {zero4, zero4};
#pragma unroll
        for (int ks = 0; ks < 4; ++ks) {
            bf16x8 a2 = *reinterpret_cast<const bf16x8*>(&lds_z[wu][l15][ks * 32 + l4 * 8]);
#pragma unroll
            for (int nn = 0; nn < 2; ++nn)
                o2[nn] = __builtin_amdgcn_mfma_f32_16x16x32_bf16(a2, w2f[ks * 2 + nn], o2[nn], 0, 0, 0);
        }

#pragma unroll
        for (int nn = 0; nn < 2; ++nn) {
#pragma unroll
            for (int r = 0; r < 4; ++r) {
                int row = blk + row0 + l4 * 4 + r;
                if (row < Btot)
                    out[(size_t)row * 32 + nn * 16 + l15] = o2[nn][r] + b2v[nn];
            }
        }
    }
}

extern "C" void kernel_launch(void* const* d_in, const int* in_sizes, int n_in,
                              void* d_out, int out_size, void* d_ws, size_t ws_size,
                              hipStream_t stream) {
    const float* agent_pos = (const float*)d_in[0];
    const float* agent_vel = (const float*)d_in[1];
    const float* rel_lm    = (const float*)d_in[2];
    const float* other_pos = (const float*)d_in[3];
    const float* lm_pos    = (const float*)d_in[4];
    const float* Wl   = (const float*)d_in[5];
    const float* bl   = (const float*)d_in[6];
    const float* Wr   = (const float*)d_in[7];
    const float* br   = (const float*)d_in[8];
    const float* We   = (const float*)d_in[9];
    const float* att  = (const float*)d_in[10];
    const float* bias = (const float*)d_in[11];
    const float* W1   = (const float*)d_in[12];
    const float* b1   = (const float*)d_in[13];
    const float* W2   = (const float*)d_in[14];
    const float* b2   = (const float*)d_in[15];
    float* out = (float*)d_out;

    int B = in_sizes[0] / 6;                  // agent_pos is [B,3,2]
    int grid = (B + 127) / 128;
    scl_fused_kernel<<<grid, 256, 0, stream>>>(
        agent_pos, agent_vel, rel_lm, other_pos, lm_pos,
        Wl, bl, Wr, br, We, att, bias, W1, b1, W2, b2, out, B);
}

// Round 21
// 29.514 us; speedup vs baseline: 1.8870x; 1.0235x over previous
//
#include <hip/hip_runtime.h>

#define NEG_SLOPE 0.2f

typedef __bf16 bf16x8 __attribute__((ext_vector_type(8)));
typedef float  f32x4  __attribute__((ext_vector_type(4)));
typedef float  f32x2  __attribute__((ext_vector_type(2)));

__device__ __forceinline__ float relu_f(float v) { return v > 0.f ? v : 0.f; }
__device__ __forceinline__ f32x2 pk_fma(f32x2 a, f32x2 b, f32x2 c) { return __builtin_elementwise_fma(a, b, c); }
__device__ __forceinline__ f32x2 pk_max(f32x2 a, f32x2 b) { return __builtin_elementwise_max(a, b); }
__device__ __forceinline__ f32x2 splat2(float s) { f32x2 r = {s, s}; return r; }
__device__ __forceinline__ f32x2 ld2(const float* p) { return *reinterpret_cast<const f32x2*>(p); }

// ============ SINGLE fused kernel: GAT + MLP. No prep, no workspace. ============
// Block = 256 threads = 4 waves, 128 samples. wave w -> g = w&1 (graph),
// sg = w>>1 (sample group). Each thread: one (sample, graph), ALL 16 channels
// as 8x f32x2 (R18/R20 structure, validated).
// R21 vs R20:
//  (1) edge geometry INLINED in the logit loop (R13 form) -> ax/ay/ad[9] arrays
//      (27 VGPRs live through logits) deleted; only d01,d02,d12 stay live.
//  (2) g1 transform skips structural zeros (xf[2..3]=0 and xf[4+2j],[5+2j]=0):
//      14 -> 10 effective features, -192 pk_fma per g1 thread.
// Barriers: ONE. LDS: h 10240 + z 17408 = 27648 B.
__global__ __launch_bounds__(256)
void scl_fused_kernel(
    const float* __restrict__ agent_pos, const float* __restrict__ agent_vel,
    const float* __restrict__ rel_lm, const float* __restrict__ other_pos,
    const float* __restrict__ lm_pos,
    const float* __restrict__ Wl, const float* __restrict__ bl,
    const float* __restrict__ Wr, const float* __restrict__ br,
    const float* __restrict__ We, const float* __restrict__ att,
    const float* __restrict__ bias,
    const float* __restrict__ W1, const float* __restrict__ b1,
    const float* __restrict__ W2, const float* __restrict__ b2,
    float* __restrict__ out, int Btot)
{
    __shared__ alignas(16) __bf16 lds_h[128][40];          // pooled GAT out (128 samples)
    __shared__ alignas(16) __bf16 lds_z[4][16][136];       // per-wave z (R8 layout)

    const int tid  = threadIdx.x;
    const int lane = tid & 63;
    const int w    = tid >> 6;
    const int g    = __builtin_amdgcn_readfirstlane(w & 1);
    const int sg   = __builtin_amdgcn_readfirstlane(w >> 1);
    const int wu   = __builtin_amdgcn_readfirstlane(w);
    const int l15  = lane & 15;
    const int l4   = lane >> 4;

    const int blk  = blockIdx.x * 128;
    const int sRow = sg * 64 + lane;            // row in lds_h
    int b = blk + sRow;
    if (b >= Btot) b = Btot - 1;                // clamp reads; barrier stays uniform

    const int o0[3] = {1, 0, 0};
    const int o1[3] = {2, 2, 1};
    const f32x4 zero4 = {0.f, 0.f, 0.f, 0.f};

    // ---- positions + 14-feature build (g-uniform branch) ----
    float px[3], py[3];
    float xf[3][14];
    if (g == 0) {
        const float2* ap = reinterpret_cast<const float2*>(agent_pos + b * 6);
#pragma unroll
        for (int j = 0; j < 3; ++j) { px[j] = ap[j].x; py[j] = ap[j].y; }
#pragma unroll
        for (int j = 0; j < 3; ++j) {
            const float2 vel = reinterpret_cast<const float2*>(agent_vel + b * 6)[j];
            const float2* rl = reinterpret_cast<const float2*>(rel_lm + b * 18 + j * 6);
            const float4 op  = reinterpret_cast<const float4*>(other_pos + b * 12)[j];
            xf[j][0] = px[j]; xf[j][1] = py[j];
            xf[j][2] = vel.x; xf[j][3] = vel.y;
            xf[j][4] = rl[0].x; xf[j][5] = rl[0].y;
            xf[j][6] = rl[1].x; xf[j][7] = rl[1].y;
            xf[j][8] = rl[2].x; xf[j][9] = rl[2].y;
            xf[j][10] = op.x; xf[j][11] = op.y; xf[j][12] = op.z; xf[j][13] = op.w;
        }
    } else {
        const float2* lp2 = reinterpret_cast<const float2*>(lm_pos + b * 18);
#pragma unroll
        for (int m = 0; m < 3; ++m) { px[m] = lp2[m].x; py[m] = lp2[m].y; }
#pragma unroll
        for (int j = 0; j < 3; ++j) {
            xf[j][0] = px[j]; xf[j][1] = py[j];
            xf[j][2] = 0.f;   xf[j][3] = 0.f;
#pragma unroll
            for (int m = 0; m < 3; ++m) {
                xf[j][4 + 2 * m] = px[m] - px[j];
                xf[j][5 + 2 * m] = py[m] - py[j];
            }
            const int a = o0[j], c2 = o1[j];
            xf[j][10] = px[a]  - px[j]; xf[j][11] = py[a]  - py[j];
            xf[j][12] = px[c2] - px[j]; xf[j][13] = py[c2] - py[j];
        }
    }

    // ---------- phase 1: transform, full 16 channels ----------
    f32x2 xl[3][8], xr[3][8];
#pragma unroll
    for (int cc = 0; cc < 8; ++cc) {
        f32x2 vbl = ld2(bl + cc * 2), vbr = ld2(br + cc * 2);
#pragma unroll
        for (int j = 0; j < 3; ++j) { xl[j][cc] = vbl; xr[j][cc] = vbr; }
    }
    if (g == 0) {
#pragma unroll
        for (int k = 0; k < 14; ++k) {
#pragma unroll
            for (int cc = 0; cc < 8; ++cc) {
                f32x2 wl2 = ld2(Wl + k * 16 + cc * 2);
                f32x2 wr2 = ld2(Wr + k * 16 + cc * 2);
#pragma unroll
                for (int j = 0; j < 3; ++j) {
                    f32x2 xk = splat2(xf[j][k]);
                    xl[j][cc] = pk_fma(xk, wl2, xl[j][cc]);
                    xr[j][cc] = pk_fma(xk, wr2, xr[j][cc]);
                }
            }
        }
    } else {
        // g1: skip structural zeros (k=2,3 globally; k=4+2j,5+2j per node)
#pragma unroll
        for (int k = 0; k < 14; ++k) {
            if (k == 2 || k == 3) continue;
#pragma unroll
            for (int cc = 0; cc < 8; ++cc) {
                f32x2 wl2 = ld2(Wl + k * 16 + cc * 2);
                f32x2 wr2 = ld2(Wr + k * 16 + cc * 2);
#pragma unroll
                for (int j = 0; j < 3; ++j) {
                    if (k == 4 + 2 * j || k == 5 + 2 * j) continue;  // self-diff = 0
                    f32x2 xk = splat2(xf[j][k]);
                    xl[j][cc] = pk_fma(xk, wl2, xl[j][cc]);
                    xr[j][cc] = pk_fma(xk, wr2, xr[j][cc]);
                }
            }
        }
    }

    // ---- pairwise distances (3 scalars only; geometry inlined below) ----
    float d01, d02, d12;
    {
        float dx, dy;
        dx = px[0] - px[1]; dy = py[0] - py[1]; d01 = sqrtf(dx * dx + dy * dy);
        dx = px[0] - px[2]; dy = py[0] - py[2]; d02 = sqrtf(dx * dx + dy * dy);
        dx = px[1] - px[2]; dy = py[1] - py[2]; d12 = sqrtf(dx * dx + dy * dy);
    }

    // ---- full logits (no exchange), edge geometry inlined (R13 form) ----
    float lg[9];
#pragma unroll
    for (int j = 0; j < 3; ++j) {
#pragma unroll
        for (int i = 0; i < 3; ++i) {
            float axv, ayv, adv;
            if (i == j) {
                const int a = o0[i], c2 = o1[i];
                axv = 0.5f * (px[a] + px[c2]) - px[i];
                ayv = 0.5f * (py[a] + py[c2]) - py[i];
                const float dA = (i == 0) ? d01 : ((i == 1) ? d01 : d02);
                const float dB = (i == 0) ? d02 : ((i == 1) ? d12 : d12);
                adv = 0.5f * (dA + dB);
            } else {
                axv = px[j] - px[i];
                ayv = py[j] - py[i];
                adv = ((i == 0 && j == 1) || (i == 1 && j == 0)) ? d01
                    : ((i == 0 && j == 2) || (i == 2 && j == 0)) ? d02 : d12;
            }
            f32x2 vax = splat2(axv), vay = splat2(ayv), vad = splat2(adv);
            f32x2 acc = {0.f, 0.f};
#pragma unroll
            for (int cc = 0; cc < 8; ++cc) {
                f32x2 gg = xl[j][cc] + xr[i][cc];
                gg = pk_fma(vax, ld2(We + cc * 2), gg);
                gg = pk_fma(vay, ld2(We + 16 + cc * 2), gg);
                gg = pk_fma(vad, ld2(We + 32 + cc * 2), gg);
                f32x2 lk = pk_max(gg, gg * splat2(NEG_SLOPE));
                acc = pk_fma(lk, ld2(att + cc * 2), acc);
            }
            lg[j * 3 + i] = acc.x + acc.y;
        }
    }

    // ---- softmax per target (once per sample-graph) + pooled relu-sum ----
    f32x2 hs[8] = {{0,0},{0,0},{0,0},{0,0},{0,0},{0,0},{0,0},{0,0}};
    const f32x2 zero2 = {0.f, 0.f};
#pragma unroll
    for (int i = 0; i < 3; ++i) {
        float e0 = __expf(lg[i]);
        float e1 = __expf(lg[3 + i]);
        float e2 = __expf(lg[6 + i]);
        float inv = __builtin_amdgcn_rcpf(e0 + e1 + e2);
        f32x2 a0 = splat2(e0 * inv), a1 = splat2(e1 * inv), a2 = splat2(e2 * inv);
#pragma unroll
        for (int cc = 0; cc < 8; ++cc) {
            f32x2 v = pk_fma(a0, xl[0][cc],
                      pk_fma(a1, xl[1][cc],
                      pk_fma(a2, xl[2][cc], ld2(bias + cc * 2))));
            hs[cc] += pk_max(v, zero2);
        }
    }

    // ---- publish pooled h (16 ch = 2x bf16x8) ----
    {
        bf16x8 hv0, hv1;
#pragma unroll
        for (int cc = 0; cc < 4; ++cc) {
            hv0[cc * 2 + 0] = (__bf16)hs[cc].x;     hv0[cc * 2 + 1] = (__bf16)hs[cc].y;
            hv1[cc * 2 + 0] = (__bf16)hs[4 + cc].x; hv1[cc * 2 + 1] = (__bf16)hs[4 + cc].y;
        }
        *reinterpret_cast<bf16x8*>(&lds_h[sRow][g * 16])     = hv0;
        *reinterpret_cast<bf16x8*>(&lds_h[sRow][g * 16 + 8]) = hv1;
    }

    // ---- MFMA B-fragments: direct strided loads from W1/W2 (R6==R7, R20 validated) ----
    bf16x8 w1f[8], w2f[8];
#pragma unroll
    for (int n = 0; n < 8; ++n) {
        const float* Wcol = W1 + (l4 * 8) * 128 + n * 16 + l15;
#pragma unroll
        for (int j = 0; j < 8; ++j) w1f[n][j] = (__bf16)Wcol[j * 128];
    }
#pragma unroll
    for (int t = 0; t < 8; ++t) {
        const int ks = t >> 1, nn = t & 1;
        const float* Wcol = W2 + (ks * 4 + l4) * 32 + nn * 16 + l15;
#pragma unroll
        for (int j = 0; j < 8; ++j) w2f[t][j] = (__bf16)Wcol[j * 16 * 32];
    }
    float b1v[8], b2v[2];
#pragma unroll
    for (int n = 0; n < 8; ++n) b1v[n] = b1[n * 16 + l15];
#pragma unroll
    for (int nn = 0; nn < 2; ++nn) b2v[nn] = b2[nn * 16 + l15];

    __syncthreads();    // the ONLY barrier: h ready

    // ---------- phase 2: MLP via MFMA 16x16x32 bf16 (validated R8), 2 tiles/wave ----------
#pragma unroll
    for (int tt = 0; tt < 2; ++tt) {
        const int tile = wu * 2 + tt;          // 0..7
        const int row0 = tile * 16;

        bf16x8 a1 = *reinterpret_cast<const bf16x8*>(&lds_h[row0 + l15][l4 * 8]);
        f32x4 acc[8];
#pragma unroll
        for (int n = 0; n < 8; ++n)
            acc[n] = __builtin_amdgcn_mfma_f32_16x16x32_bf16(a1, w1f[n], zero4, 0, 0, 0);
#pragma unroll
        for (int r = 0; r < 4; ++r) {
            bf16x8 zv;
#pragma unroll
            for (int n = 0; n < 8; ++n) zv[n] = (__bf16)relu_f(acc[n][r] + b1v[n]);
            *reinterpret_cast<bf16x8*>(&lds_z[wu][l4 * 4 + r][l15 * 8]) = zv;
        }

        f32x4 o2[2] = {zero4, zero4};
#pragma unroll
        for (int ks = 0; ks < 4; ++ks) {
            bf16x8 a2 = *reinterpret_cast<const bf16x8*>(&lds_z[wu][l15][ks * 32 + l4 * 8]);
#pragma unroll
            for (int nn = 0; nn < 2; ++nn)
                o2[nn] = __builtin_amdgcn_mfma_f32_16x16x32_bf16(a2, w2f[ks * 2 + nn], o2[nn], 0, 0, 0);
        }

#pragma unroll
        for (int nn = 0; nn < 2; ++nn) {
#pragma unroll
            for (int r = 0; r < 4; ++r) {
                int row = blk + row0 + l4 * 4 + r;
                if (row < Btot)
                    out[(size_t)row * 32 + nn * 16 + l15] = o2[nn][r] + b2v[nn];
            }
        }
    }
}

extern "C" void kernel_launch(void* const* d_in, const int* in_sizes, int n_in,
                              void* d_out, int out_size, void* d_ws, size_t ws_size,
                              hipStream_t stream) {
    const float* agent_pos = (const float*)d_in[0];
    const float* agent_vel = (const float*)d_in[1];
    const float* rel_lm    = (const float*)d_in[2];
    const float* other_pos = (const float*)d_in[3];
    const float* lm_pos    = (const float*)d_in[4];
    const float* Wl   = (const float*)d_in[5];
    const float* bl   = (const float*)d_in[6];
    const float* Wr   = (const float*)d_in[7];
    const float* br   = (const float*)d_in[8];
    const float* We   = (const float*)d_in[9];
    const float* att  = (const float*)d_in[10];
    const float* bias = (const float*)d_in[11];
    const float* W1   = (const float*)d_in[12];
    const float* b1   = (const float*)d_in[13];
    const float* W2   = (const float*)d_in[14];
    const float* b2   = (const float*)d_in[15];
    float* out = (float*)d_out;

    int B = in_sizes[0] / 6;                  // agent_pos is [B,3,2]
    int grid = (B + 127) / 128;
    scl_fused_kernel<<<grid, 256, 0, stream>>>(
        agent_pos, agent_vel, rel_lm, other_pos, lm_pos,
        Wl, bl, Wr, br, We, att, bias, W1, b1, W2, b2, out, B);
}